// Round 10
// baseline (136.699 us; speedup 1.0000x reference)
//
#include <hip/hip_runtime.h>

// ---------------------------------------------------------------------------
// MultiheadAttention: out = (softmax((Xq Wq^T + bq)(Xb Wk^T + bk)^T / 8) (Xb Wv^T + bv)) Wo^T + bo
// B=2, S=2048, D=1024, H=16, hd=64.  All GEMMs + attention in bf16 MFMA, fp32 accum.
// ---------------------------------------------------------------------------

#define BDIM   2
#define SDIM   2048
#define DDIM   1024
#define HEADS  16
#define HD     64
#define MROWS  (BDIM * SDIM)   // 4096

typedef float  f32x4  __attribute__((ext_vector_type(4)));
typedef __bf16 bf16x8 __attribute__((ext_vector_type(8)));
typedef __bf16 bf16x4 __attribute__((ext_vector_type(4)));

// Q scale: 1/sqrt(hd) * log2(e)  (softmax computed in exp2 domain)
#define QSCALE 0.18033688011112042f

__device__ __forceinline__ void stage16(const void* g, void* l) {
    // global -> LDS direct copy, 16B per lane, dest = wave-uniform base + lane*16
    __builtin_amdgcn_global_load_lds((const __attribute__((address_space(1))) void*)g,
                                     (__attribute__((address_space(3))) void*)l,
                                     16, 0, 0);
}

// ---------------------------------------------------------------------------
// ALL fp32 -> bf16 conversions in ONE launch.
// chunks: query 524288, bank 524288, then 4 weights x 131072 (8 floats each).
// ---------------------------------------------------------------------------
__global__ __launch_bounds__(256) void cvt_all(
    const float* __restrict__ q, const float* __restrict__ bank,
    const float* __restrict__ Wq, const float* __restrict__ Wk,
    const float* __restrict__ Wv, const float* __restrict__ Wo,
    __bf16* __restrict__ xq, __bf16* __restrict__ xkv,
    __bf16* __restrict__ wq, __bf16* __restrict__ wk,
    __bf16* __restrict__ wv, __bf16* __restrict__ wo) {
    const int i = blockIdx.x * 256 + threadIdx.x;   // 0..1572863
    const float* in;
    __bf16* out;
    int off;
    if (i < 524288)       { in = q;    out = xq;  off = i; }
    else if (i < 1048576) { in = bank; out = xkv; off = i - 524288; }
    else {
        const int j = i - 1048576;
        const int sel = j >> 17;
        off = j & 131071;
        in  = (sel == 0) ? Wq : (sel == 1) ? Wk : (sel == 2) ? Wv : Wo;
        out = (sel == 0) ? wq : (sel == 1) ? wk : (sel == 2) ? wv : wo;
    }
    const float4* p = (const float4*)in;
    float4 a = p[2 * off];
    float4 c = p[2 * off + 1];
    bf16x8 o;
    o[0] = (__bf16)a.x; o[1] = (__bf16)a.y; o[2] = (__bf16)a.z; o[3] = (__bf16)a.w;
    o[4] = (__bf16)c.x; o[5] = (__bf16)c.y; o[6] = (__bf16)c.z; o[7] = (__bf16)c.w;
    *(bf16x8*)(out + 8 * off) = o;
}

// ---------------------------------------------------------------------------
// B^T GEMM v2: BK=64, XOR-swizzled LDS (conflict-free ds_read_b128), 2-barrier
// loop, 32 MFMA : 16 ds_read per k-step, 16 barrier rounds.
// Swizzle (rule 21): linear global_load_lds dest; global source granule
// (t&7)^(row&7); fragment read granule (h*4+q4)^(row&7).  XOR spans all 8
// 16B-granules of a 64-elem row -> 2 lanes/bank = conflict-free (m136).
// MODE 0: 128x128 tile, z selects {Q,K,V}; bf16 head-split outputs.
// MODE 2: 128x64 tile (2 blocks/CU tail launch), fp32 out.
// ---------------------------------------------------------------------------
template <int MODE>
__global__ __launch_bounds__(256) void gemm_bt(
    const __bf16* __restrict__ Aq, const __bf16* __restrict__ Akv,
    const __bf16* __restrict__ W0, const __bf16* __restrict__ W1,
    const __bf16* __restrict__ W2,
    const float* __restrict__ b0, const float* __restrict__ b1,
    const float* __restrict__ b2,
    __bf16* __restrict__ Qo, __bf16* __restrict__ Ko, __bf16* __restrict__ Vo,
    float* __restrict__ Fo) {
    constexpr int NF = (MODE == 2) ? 2 : 4;        // n-fragments per wave
    constexpr int NCOL = NF * 32;                  // block col-tile (64 or 128)
    __shared__ __align__(16) __bf16 ldsA[128 * 64];
    __shared__ __align__(16) __bf16 ldsB[NCOL * 64];

    const int t = threadIdx.x;
    const int l = t & 63;
    const int w = t >> 6;
    const int z = (MODE == 0) ? (int)blockIdx.z : 0;

    const __bf16* A  = (MODE == 0 && z != 0) ? Akv : Aq;
    const __bf16* Wm = (z == 0) ? W0 : (z == 1 ? W1 : W2);
    const float*  bias = (z == 0) ? b0 : (z == 1 ? b1 : b2);

    const int row0 = blockIdx.y * 128;
    const int col0 = blockIdx.x * NCOL;

    // staging: thread t fills LDS row (t>>3)+32c, granule t&7; source granule
    // XOR'd so that the LINEAR LDS write lands swizzled data (rule 21).
    const int srow = t >> 3;                         // 0..31
    const int sg   = (t & 7) ^ (srow & 7);           // swizzled source granule
    const __bf16* ga = A  + (size_t)(row0 + srow) * DDIM + sg * 8;
    const __bf16* gb = Wm + (size_t)(col0 + srow) * DDIM + sg * 8;
    __bf16* la = ldsA + (t & ~63) * 8;               // wave-uniform dest base
    __bf16* lb = ldsB + (t & ~63) * 8;

    const int wm = w >> 1, wn = w & 1;
    const int i15 = l & 15;
    const int q4 = l >> 4;
    const int xr = i15 & 7;                          // fragment row & 7

    // fragment read offsets (elements): row*64 + ((h*4+q4)^xr)*8
    int ao[4][2], bo[NF][2];
#pragma unroll
    for (int m = 0; m < 4; ++m)
#pragma unroll
        for (int h = 0; h < 2; ++h)
            ao[m][h] = (wm * 64 + m * 16 + i15) * 64 + (((h * 4 + q4) ^ xr) << 3);
#pragma unroll
    for (int n = 0; n < NF; ++n)
#pragma unroll
        for (int h = 0; h < 2; ++h)
            bo[n][h] = (wn * (NF * 16) + n * 16 + i15) * 64 + (((h * 4 + q4) ^ xr) << 3);

    f32x4 acc[4][NF] = {};

    for (int kb = 0; kb < DDIM; kb += 64) {
        __syncthreads();
        stage16(ga + kb,             la);
        stage16(ga + kb + 32 * DDIM, la + 2048);
        stage16(ga + kb + 64 * DDIM, la + 4096);
        stage16(ga + kb + 96 * DDIM, la + 6144);
        stage16(gb + kb,             lb);
        stage16(gb + kb + 32 * DDIM, lb + 2048);
        if constexpr (MODE == 0) {
            stage16(gb + kb + 64 * DDIM, lb + 4096);
            stage16(gb + kb + 96 * DDIM, lb + 6144);
        }
        __syncthreads();

#pragma unroll
        for (int h = 0; h < 2; ++h) {
            bf16x8 af[4], bf[NF];
#pragma unroll
            for (int m = 0; m < 4; ++m) af[m] = *(const bf16x8*)(ldsA + ao[m][h]);
#pragma unroll
            for (int n = 0; n < NF; ++n) bf[n] = *(const bf16x8*)(ldsB + bo[n][h]);
#pragma unroll
            for (int m = 0; m < 4; ++m)
#pragma unroll
                for (int n = 0; n < NF; ++n)
                    acc[m][n] = __builtin_amdgcn_mfma_f32_16x16x32_bf16(af[m], bf[n], acc[m][n], 0, 0, 0);
        }
    }

    // ---- epilogue: C/D layout col = lane&15, row = (lane>>4)*4 + j ----
#pragma unroll
    for (int m = 0; m < 4; ++m) {
        const int rbase = row0 + wm * 64 + m * 16 + (l >> 4) * 4;
#pragma unroll
        for (int n = 0; n < NF; ++n) {
            const int col = col0 + wn * (NF * 16) + n * 16 + (l & 15);
            const float bv = bias[col];
            if constexpr (MODE == 0) {
                const int hh = col >> 6, d = col & 63;
#pragma unroll
                for (int j = 0; j < 4; ++j) {
                    const int r = rbase + j;
                    const int b = r >> 11, s = r & 2047;
                    const float v = acc[m][n][j] + bv;
                    if (z == 0) {
                        Qo[(((b * HEADS + hh) * SDIM + s) << 6) + d] = (__bf16)(v * QSCALE);
                    } else if (z == 1) {
                        Ko[(((b * HEADS + hh) * SDIM + s) << 6) + d] = (__bf16)v;
                    } else {  // V stored transposed: [B,H,hd,S]
                        Vo[(((b * HEADS + hh) * HD + d) << 11) + s] = (__bf16)v;
                    }
                }
            } else {
#pragma unroll
                for (int j = 0; j < 4; ++j) {
                    Fo[(size_t)(rbase + j) * DDIM + col] = acc[m][n][j] + bv;
                }
            }
        }
    }
}

// ---------------------------------------------------------------------------
// Flash attention v7b (unchanged from round 9): 512 blocks x 512 threads =
// 8 waves x 16 q-rows, KVBLK=128, XCD head-clustering, swapped QK^T +
// sigma-permuted K staging, XOR-swizzled LDS, no-max exp2 softmax, row-sum
// on the MFMA pipe.  LDS 64 KB.
// ---------------------------------------------------------------------------
__global__ __launch_bounds__(512) void attn_fwd(const __bf16* __restrict__ Qb,
                                                const __bf16* __restrict__ Kb,
                                                const __bf16* __restrict__ Vtb,
                                                __bf16* __restrict__ Cb) {
    __shared__ __align__(16) __bf16 ldsK[2][2][64 * 64];
    __shared__ __align__(16) __bf16 ldsV[2][2][64 * 64];

    const int t = threadIdx.x;        // 0..511
    const int l = t & 63;
    const int w = t >> 6;             // 0..7
    const int i15 = l & 15;
    const int q4 = l >> 4;

    // --- XCD head-clustering decode (bijective on 512 blocks) ---
    const int bid  = blockIdx.x;
    const int xcd  = bid & 7;
    const int wloc = bid >> 3;               // 0..63 within XCD
    const int bh   = xcd * 4 + (wloc >> 4);  // 4 (b,h) pairs per XCD
    const int qb   = wloc & 15;              // q-block within head (consecutive)
    const int b    = bh >> 4;
    const int h    = bh & 15;
    const size_t base = (size_t)bh * SDIM * HD;
    const int q0 = qb * 128;

    // Q fragments (B-operand of swapped QK^T): col=q=i15, k-dim=d
    const __bf16* qp = Qb + base + (size_t)(q0 + w * 16 + i15) * HD + q4 * 8;
    const bf16x8 qf0 = *(const bf16x8*)(qp);
    const bf16x8 qf1 = *(const bf16x8*)(qp + 32);

    // --- staging source addresses (rule 21: linear LDS dest, permuted source)
    const int r0 = t >> 3;                    // LDS row this thread fills
    const int sl = (t & 7) ^ (r0 & 7);        // source slot = phys slot ^ row&7
    const int sig0 = ((r0 >> 5) << 5) | (((r0 >> 2) & 3) << 3)
                   | (((r0 >> 4) & 1) << 2) | (r0 & 3);      // sigma-permuted K row
    const __bf16* gk = Kb  + base + (size_t)sig0 * HD + sl * 8;
    const __bf16* gv = Vtb + base + (size_t)r0 * SDIM + sl * 8;
    const int wb = (t & ~63) * 8;             // wave-uniform LDS element base

    // --- swizzled read offsets (elements), same table for K and V reads ---
    const int xr = i15 & 7;
    int off[4][2];
#pragma unroll
    for (int n = 0; n < 4; ++n)
#pragma unroll
        for (int hh = 0; hh < 2; ++hh)
            off[n][hh] = (n * 16 + i15) * 64 + (((hh * 4 + q4) ^ xr) << 3);

    // ones fragment for the MFMA row-sum
    bf16x8 ones;
#pragma unroll
    for (int j = 0; j < 8; ++j) ones[j] = (__bf16)1.0f;

    f32x4 c[4] = {};
    f32x4 lsum = {};

    // prologue: stage round 0 (two 64-row sub-tiles of K and V) into buffer 0
    stage16(gk,           &ldsK[0][0][wb]);
    stage16(gk + 64 * HD, &ldsK[0][1][wb]);
    stage16(gv,           &ldsV[0][0][wb]);
    stage16(gv + 64,      &ldsV[0][1][wb]);

#pragma unroll 2
    for (int r = 0; r < SDIM / 128; ++r) {
        const int bb = r & 1;
        __syncthreads();   // buf[bb] staged & prev compute on buf[bb^1] done

        if (r + 1 < SDIM / 128) {
            const int s0 = (r + 1) * 128;
            stage16(gk + (size_t)s0 * HD,        &ldsK[bb ^ 1][0][wb]);
            stage16(gk + (size_t)(s0 + 64) * HD, &ldsK[bb ^ 1][1][wb]);
            stage16(gv + s0,                     &ldsV[bb ^ 1][0][wb]);
            stage16(gv + s0 + 64,                &ldsV[bb ^ 1][1][wb]);
        }

        const __bf16* lk0 = &ldsK[bb][0][0];
        const __bf16* lk1 = &ldsK[bb][1][0];
        const __bf16* lv0 = &ldsV[bb][0][0];
        const __bf16* lv1 = &ldsV[bb][1][0];

        // ---- QK^T (swapped), both halves: sA/sB hold S^T[k-block n][q] ----
        f32x4 sA[4] = {}, sB[4] = {};
        __builtin_amdgcn_s_setprio(1);
#pragma unroll
        for (int n = 0; n < 4; ++n) {
            bf16x8 k0 = *(const bf16x8*)(lk0 + off[n][0]);
            bf16x8 k1 = *(const bf16x8*)(lk0 + off[n][1]);
            sA[n] = __builtin_amdgcn_mfma_f32_16x16x32_bf16(k0, qf0, sA[n], 0, 0, 0);
            sA[n] = __builtin_amdgcn_mfma_f32_16x16x32_bf16(k1, qf1, sA[n], 0, 0, 0);
        }
#pragma unroll
        for (int n = 0; n < 4; ++n) {
            bf16x8 k0 = *(const bf16x8*)(lk1 + off[n][0]);
            bf16x8 k1 = *(const bf16x8*)(lk1 + off[n][1]);
            sB[n] = __builtin_amdgcn_mfma_f32_16x16x32_bf16(k0, qf0, sB[n], 0, 0, 0);
            sB[n] = __builtin_amdgcn_mfma_f32_16x16x32_bf16(k1, qf1, sB[n], 0, 0, 0);
        }
        __builtin_amdgcn_s_setprio(0);

        // ---- softmax numerator: raw exp2 (no max, no cross-lane), both halves ----
#pragma unroll
        for (int n = 0; n < 4; ++n)
#pragma unroll
            for (int j = 0; j < 4; ++j) {
                sA[n][j] = exp2f(sA[n][j]);
                sB[n][j] = exp2f(sB[n][j]);
            }

        // ---- pack P^T fragments (lane-local; k-order matches V columns) ----
        bf16x8 paA0, paB0, paA1, paB1;
#pragma unroll
        for (int j = 0; j < 4; ++j) {
            paA0[j]     = (__bf16)sA[0][j];
            paA0[j + 4] = (__bf16)sA[1][j];
            paB0[j]     = (__bf16)sA[2][j];
            paB0[j + 4] = (__bf16)sA[3][j];
            paA1[j]     = (__bf16)sB[0][j];
            paA1[j + 4] = (__bf16)sB[1][j];
            paB1[j]     = (__bf16)sB[2][j];
            paB1[j + 4] = (__bf16)sB[3][j];
        }

        // ---- PV + MFMA row-sum, both halves ----
        __builtin_amdgcn_s_setprio(1);
        lsum = __builtin_amdgcn_mfma_f32_16x16x32_bf16(ones, paA0, lsum, 0, 0, 0);
        lsum = __builtin_amdgcn_mfma_f32_16x16x32_bf16(ones, paB0, lsum, 0, 0, 0);
        lsum = __builtin_amdgcn_mfma_f32_16x16x32_bf16(ones, paA1, lsum, 0, 0, 0);
        lsum = __builtin_amdgcn_mfma_f32_16x16x32_bf16(ones, paB1, lsum, 0, 0, 0);
#pragma unroll
        for (int n2 = 0; n2 < 4; ++n2) {
            bf16x8 v0 = *(const bf16x8*)(lv0 + off[n2][0]);
            bf16x8 v1 = *(const bf16x8*)(lv0 + off[n2][1]);
            c[n2] = __builtin_amdgcn_mfma_f32_16x16x32_bf16(v0, paA0, c[n2], 0, 0, 0);
            c[n2] = __builtin_amdgcn_mfma_f32_16x16x32_bf16(v1, paB0, c[n2], 0, 0, 0);
            bf16x8 u0 = *(const bf16x8*)(lv1 + off[n2][0]);
            bf16x8 u1 = *(const bf16x8*)(lv1 + off[n2][1]);
            c[n2] = __builtin_amdgcn_mfma_f32_16x16x32_bf16(u0, paA1, c[n2], 0, 0, 0);
            c[n2] = __builtin_amdgcn_mfma_f32_16x16x32_bf16(u1, paB1, c[n2], 0, 0, 0);
        }
        __builtin_amdgcn_s_setprio(0);
    }

    // ---- write ctx (merged heads, bf16): [B, S, D], 8B vector stores ----
    const float inv = 1.0f / lsum[0];
    const int q = q0 + w * 16 + i15;
#pragma unroll
    for (int n2 = 0; n2 < 4; ++n2) {
        bf16x4 o;
#pragma unroll
        for (int j = 0; j < 4; ++j) o[j] = (__bf16)(c[n2][j] * inv);
        *(bf16x4*)(Cb + (size_t)(b * SDIM + q) * DDIM + h * HD + n2 * 16 + q4 * 4) = o;
    }
}

// ---------------------------------------------------------------------------
extern "C" void kernel_launch(void* const* d_in, const int* in_sizes, int n_in,
                              void* d_out, int out_size, void* d_ws, size_t ws_size,
                              hipStream_t stream) {
    const float* query = (const float*)d_in[0];
    const float* bank  = (const float*)d_in[1];
    const float* Wq = (const float*)d_in[2];
    const float* bq = (const float*)d_in[3];
    const float* Wk = (const float*)d_in[4];
    const float* bk = (const float*)d_in[5];
    const float* Wv = (const float*)d_in[6];
    const float* bv = (const float*)d_in[7];
    const float* Wo = (const float*)d_in[8];
    const float* bo = (const float*)d_in[9];
    float* out = (float*)d_out;

    char* ws = (char*)d_ws;
    __bf16* xq  = (__bf16*)(ws);                    // 8 MB  [4096,1024] (reused as ctx)
    __bf16* xkv = (__bf16*)(ws + (8u  << 20));      // 8 MB
    __bf16* wq  = (__bf16*)(ws + (16u << 20));      // 2 MB
    __bf16* wk  = (__bf16*)(ws + (18u << 20));      // 2 MB
    __bf16* wv  = (__bf16*)(ws + (20u << 20));      // 2 MB
    __bf16* wo  = (__bf16*)(ws + (22u << 20));      // 2 MB
    __bf16* qbuf = (__bf16*)(ws + (24u << 20));     // 8 MB [B,H,S,hd] (scaled)
    __bf16* kbuf = (__bf16*)(ws + (32u << 20));     // 8 MB [B,H,S,hd]
    __bf16* vtbuf = (__bf16*)(ws + (40u << 20));    // 8 MB [B,H,hd,S]
    __bf16* ctx = xq;                               // alias: xq dead after QKV gemm

    // fp32 -> bf16 (single launch for all 6 tensors)
    cvt_all<<<6144, 256, 0, stream>>>(query, bank, Wq, Wk, Wv, Wo,
                                      xq, xkv, wq, wk, wv, wo);

    // fused QKV projections (z=0 Q, z=1 K, z=2 V^T) — 768 blocks, 3/CU
    gemm_bt<0><<<dim3(8, 32, 3), 256, 0, stream>>>(
        xq, xkv, wq, wk, wv, bq, bk, bv, qbuf, kbuf, vtbuf, nullptr);

    // flash attention (1D grid, XCD head-clustering decode inside)
    attn_fwd<<<512, 512, 0, stream>>>(qbuf, kbuf, vtbuf, ctx);

    // output projection (fp32 out) — 128x64 tile, 512 blocks, 2/CU
    gemm_bt<2><<<dim3(16, 32, 1), 256, 0, stream>>>(
        ctx, nullptr, wo, nullptr, nullptr, bo, nullptr, nullptr,
        nullptr, nullptr, nullptr, out);
}

// Round 11
// 135.792 us; speedup vs baseline: 1.0067x; 1.0067x over previous
//
#include <hip/hip_runtime.h>

// ---------------------------------------------------------------------------
// MultiheadAttention: out = (softmax((Xq Wq^T + bq)(Xb Wk^T + bk)^T / 8) (Xb Wv^T + bv)) Wo^T + bo
// B=2, S=2048, D=1024, H=16, hd=64.  All GEMMs + attention in bf16 MFMA, fp32 accum.
// ---------------------------------------------------------------------------

#define BDIM   2
#define SDIM   2048
#define DDIM   1024
#define HEADS  16
#define HD     64
#define MROWS  (BDIM * SDIM)   // 4096

typedef float  f32x4  __attribute__((ext_vector_type(4)));
typedef __bf16 bf16x8 __attribute__((ext_vector_type(8)));
typedef __bf16 bf16x4 __attribute__((ext_vector_type(4)));

// Q scale: 1/sqrt(hd) * log2(e)  (softmax computed in exp2 domain)
#define QSCALE 0.18033688011112042f

__device__ __forceinline__ void stage16(const void* g, void* l) {
    // global -> LDS direct copy, 16B per lane, dest = wave-uniform base + lane*16
    __builtin_amdgcn_global_load_lds((const __attribute__((address_space(1))) void*)g,
                                     (__attribute__((address_space(3))) void*)l,
                                     16, 0, 0);
}

// ---------------------------------------------------------------------------
// ALL fp32 -> bf16 conversions in ONE launch.
// chunks: query 524288, bank 524288, then 4 weights x 131072 (8 floats each).
// ---------------------------------------------------------------------------
__global__ __launch_bounds__(256) void cvt_all(
    const float* __restrict__ q, const float* __restrict__ bank,
    const float* __restrict__ Wq, const float* __restrict__ Wk,
    const float* __restrict__ Wv, const float* __restrict__ Wo,
    __bf16* __restrict__ xq, __bf16* __restrict__ xkv,
    __bf16* __restrict__ wq, __bf16* __restrict__ wk,
    __bf16* __restrict__ wv, __bf16* __restrict__ wo) {
    const int i = blockIdx.x * 256 + threadIdx.x;   // 0..1572863
    const float* in;
    __bf16* out;
    int off;
    if (i < 524288)       { in = q;    out = xq;  off = i; }
    else if (i < 1048576) { in = bank; out = xkv; off = i - 524288; }
    else {
        const int j = i - 1048576;
        const int sel = j >> 17;
        off = j & 131071;
        in  = (sel == 0) ? Wq : (sel == 1) ? Wk : (sel == 2) ? Wv : Wo;
        out = (sel == 0) ? wq : (sel == 1) ? wk : (sel == 2) ? wv : wo;
    }
    const float4* p = (const float4*)in;
    float4 a = p[2 * off];
    float4 c = p[2 * off + 1];
    bf16x8 o;
    o[0] = (__bf16)a.x; o[1] = (__bf16)a.y; o[2] = (__bf16)a.z; o[3] = (__bf16)a.w;
    o[4] = (__bf16)c.x; o[5] = (__bf16)c.y; o[6] = (__bf16)c.z; o[7] = (__bf16)c.w;
    *(bf16x8*)(out + 8 * off) = o;
}

// ---------------------------------------------------------------------------
// B^T GEMM (round-9 proven body: BK=32, 16 KB LDS, 2-barrier loop) + XCD
// panel-clustering: 1D grid, XCD c = bid&7 owns a CONTIGUOUS run of 96 (MODE
// 0) / 64 (MODE 2) blocks -> the A row-panels it touches stay resident in its
// private L2 and are fetched once, instead of all 8 XCDs fetching every panel
// (round-10 counters: FETCH_SIZE 101 MB vs 22 MB footprint, MfmaUtil 16%).
// out[r][n] = sum_k A[r][k] * W[n][k] + bias.
// MODE 0: 128x128 tile, 768 blocks; z selects {Q,K,V}; bf16 head-split out
//         (V transposed [B,H,hd,S] via scatter epilogue).
// MODE 2: 128x64 tile, 512 blocks (2/CU tail launch), fp32 out.
// ---------------------------------------------------------------------------
template <int MODE>
__global__ __launch_bounds__(256) void gemm_bt(
    const __bf16* __restrict__ Aq, const __bf16* __restrict__ Akv,
    const __bf16* __restrict__ W0, const __bf16* __restrict__ W1,
    const __bf16* __restrict__ W2,
    const float* __restrict__ b0, const float* __restrict__ b1,
    const float* __restrict__ b2,
    __bf16* __restrict__ Qo, __bf16* __restrict__ Ko, __bf16* __restrict__ Vo,
    float* __restrict__ Fo) {
    constexpr int NF = (MODE == 2) ? 2 : 4;        // n-fragments per wave
    constexpr int NCOL = NF * 32;                  // block col-tile (64 or 128)
    __shared__ __align__(16) __bf16 ldsA[128 * 32];
    __shared__ __align__(16) __bf16 ldsB[(NCOL)*32];

    const int t = threadIdx.x;
    const int l = t & 63;
    const int w = t >> 6;

    // --- XCD panel-clustering decode (bijective; HW: XCD = dispatch_id & 7) ---
    const int d = blockIdx.x;
    const int c = d & 7;
    const int i = d >> 3;                          // 0..95 (MODE 0) / 0..63
    const int L = (MODE == 0) ? c * 96 + i : c * 64 + i;
    const int bx = (MODE == 0) ? (L & 7) : (L & 15);
    const int by = (MODE == 0) ? ((L >> 3) & 31) : (L >> 4);
    const int z  = (MODE == 0) ? (L >> 8) : 0;

    const __bf16* A  = (MODE == 0 && z != 0) ? Akv : Aq;
    const __bf16* Wm = (z == 0) ? W0 : (z == 1 ? W1 : W2);
    const float*  bias = (z == 0) ? b0 : (z == 1 ? b1 : b2);

    const int row0 = by * 128;
    const int col0 = bx * NCOL;

    const __bf16* ga = A  + (size_t)(row0 + (t >> 2)) * DDIM + (t & 3) * 8;
    const __bf16* gb = Wm + (size_t)(col0 + (t >> 2)) * DDIM + (t & 3) * 8;
    __bf16* la = ldsA + (t & ~63) * 8;  // wave-uniform base
    __bf16* lb = ldsB + (t & ~63) * 8;

    const int wm = w >> 1, wn = w & 1;
    const int aoff = (wm * 64 + (l & 15)) * 32 + (l >> 4) * 8;
    const int boff = (wn * (NF * 16) + (l & 15)) * 32 + (l >> 4) * 8;

    f32x4 acc[4][NF] = {};

    for (int kb = 0; kb < DDIM; kb += 32) {
        __syncthreads();
        stage16(ga + kb,             la);
        stage16(ga + kb + 64 * DDIM, la + 2048);
        stage16(gb + kb,             lb);
        if constexpr (MODE == 0)
            stage16(gb + kb + 64 * DDIM, lb + 2048);
        __syncthreads();

        bf16x8 af[4], bf[NF];
#pragma unroll
        for (int m = 0; m < 4; ++m) af[m] = *(const bf16x8*)(ldsA + aoff + m * 16 * 32);
#pragma unroll
        for (int n = 0; n < NF; ++n) bf[n] = *(const bf16x8*)(ldsB + boff + n * 16 * 32);
#pragma unroll
        for (int m = 0; m < 4; ++m)
#pragma unroll
            for (int n = 0; n < NF; ++n)
                acc[m][n] = __builtin_amdgcn_mfma_f32_16x16x32_bf16(af[m], bf[n], acc[m][n], 0, 0, 0);
    }

    // ---- epilogue: C/D layout col = lane&15, row = (lane>>4)*4 + j ----
#pragma unroll
    for (int m = 0; m < 4; ++m) {
        const int rbase = row0 + wm * 64 + m * 16 + (l >> 4) * 4;
#pragma unroll
        for (int n = 0; n < NF; ++n) {
            const int col = col0 + wn * (NF * 16) + n * 16 + (l & 15);
            const float bv = bias[col];
            if constexpr (MODE == 0) {
                const int hh = col >> 6, dd = col & 63;
#pragma unroll
                for (int j = 0; j < 4; ++j) {
                    const int r = rbase + j;
                    const int b = r >> 11, s = r & 2047;
                    const float v = acc[m][n][j] + bv;
                    if (z == 0) {
                        Qo[(((b * HEADS + hh) * SDIM + s) << 6) + dd] = (__bf16)(v * QSCALE);
                    } else if (z == 1) {
                        Ko[(((b * HEADS + hh) * SDIM + s) << 6) + dd] = (__bf16)v;
                    } else {  // V stored transposed: [B,H,hd,S]
                        Vo[(((b * HEADS + hh) * HD + dd) << 11) + s] = (__bf16)v;
                    }
                }
            } else {
#pragma unroll
                for (int j = 0; j < 4; ++j) {
                    Fo[(size_t)(rbase + j) * DDIM + col] = acc[m][n][j] + bv;
                }
            }
        }
    }
}

// ---------------------------------------------------------------------------
// Flash attention v7b (unchanged): 512 blocks x 512 threads = 8 waves x 16
// q-rows, KVBLK=128, XCD head-clustering, swapped QK^T + sigma-permuted K
// staging, XOR-swizzled LDS, no-max exp2 softmax, row-sum on the MFMA pipe.
// ---------------------------------------------------------------------------
__global__ __launch_bounds__(512) void attn_fwd(const __bf16* __restrict__ Qb,
                                                const __bf16* __restrict__ Kb,
                                                const __bf16* __restrict__ Vtb,
                                                __bf16* __restrict__ Cb) {
    __shared__ __align__(16) __bf16 ldsK[2][2][64 * 64];
    __shared__ __align__(16) __bf16 ldsV[2][2][64 * 64];

    const int t = threadIdx.x;        // 0..511
    const int l = t & 63;
    const int w = t >> 6;             // 0..7
    const int i15 = l & 15;
    const int q4 = l >> 4;

    // --- XCD head-clustering decode (bijective on 512 blocks) ---
    const int bid  = blockIdx.x;
    const int xcd  = bid & 7;
    const int wloc = bid >> 3;               // 0..63 within XCD
    const int bh   = xcd * 4 + (wloc >> 4);  // 4 (b,h) pairs per XCD
    const int qb   = wloc & 15;              // q-block within head (consecutive)
    const int b    = bh >> 4;
    const int h    = bh & 15;
    const size_t base = (size_t)bh * SDIM * HD;
    const int q0 = qb * 128;

    // Q fragments (B-operand of swapped QK^T): col=q=i15, k-dim=d
    const __bf16* qp = Qb + base + (size_t)(q0 + w * 16 + i15) * HD + q4 * 8;
    const bf16x8 qf0 = *(const bf16x8*)(qp);
    const bf16x8 qf1 = *(const bf16x8*)(qp + 32);

    // --- staging source addresses (rule 21: linear LDS dest, permuted source)
    const int r0 = t >> 3;                    // LDS row this thread fills
    const int sl = (t & 7) ^ (r0 & 7);        // source slot = phys slot ^ row&7
    const int sig0 = ((r0 >> 5) << 5) | (((r0 >> 2) & 3) << 3)
                   | (((r0 >> 4) & 1) << 2) | (r0 & 3);      // sigma-permuted K row
    const __bf16* gk = Kb  + base + (size_t)sig0 * HD + sl * 8;
    const __bf16* gv = Vtb + base + (size_t)r0 * SDIM + sl * 8;
    const int wb = (t & ~63) * 8;             // wave-uniform LDS element base

    // --- swizzled read offsets (elements), same table for K and V reads ---
    const int xr = i15 & 7;
    int off[4][2];
#pragma unroll
    for (int n = 0; n < 4; ++n)
#pragma unroll
        for (int hh = 0; hh < 2; ++hh)
            off[n][hh] = (n * 16 + i15) * 64 + (((hh * 4 + q4) ^ xr) << 3);

    // ones fragment for the MFMA row-sum
    bf16x8 ones;
#pragma unroll
    for (int j = 0; j < 8; ++j) ones[j] = (__bf16)1.0f;

    f32x4 c[4] = {};
    f32x4 lsum = {};

    // prologue: stage round 0 (two 64-row sub-tiles of K and V) into buffer 0
    stage16(gk,           &ldsK[0][0][wb]);
    stage16(gk + 64 * HD, &ldsK[0][1][wb]);
    stage16(gv,           &ldsV[0][0][wb]);
    stage16(gv + 64,      &ldsV[0][1][wb]);

#pragma unroll 2
    for (int r = 0; r < SDIM / 128; ++r) {
        const int bb = r & 1;
        __syncthreads();   // buf[bb] staged & prev compute on buf[bb^1] done

        if (r + 1 < SDIM / 128) {
            const int s0 = (r + 1) * 128;
            stage16(gk + (size_t)s0 * HD,        &ldsK[bb ^ 1][0][wb]);
            stage16(gk + (size_t)(s0 + 64) * HD, &ldsK[bb ^ 1][1][wb]);
            stage16(gv + s0,                     &ldsV[bb ^ 1][0][wb]);
            stage16(gv + s0 + 64,                &ldsV[bb ^ 1][1][wb]);
        }

        const __bf16* lk0 = &ldsK[bb][0][0];
        const __bf16* lk1 = &ldsK[bb][1][0];
        const __bf16* lv0 = &ldsV[bb][0][0];
        const __bf16* lv1 = &ldsV[bb][1][0];

        // ---- QK^T (swapped), both halves: sA/sB hold S^T[k-block n][q] ----
        f32x4 sA[4] = {}, sB[4] = {};
        __builtin_amdgcn_s_setprio(1);
#pragma unroll
        for (int n = 0; n < 4; ++n) {
            bf16x8 k0 = *(const bf16x8*)(lk0 + off[n][0]);
            bf16x8 k1 = *(const bf16x8*)(lk0 + off[n][1]);
            sA[n] = __builtin_amdgcn_mfma_f32_16x16x32_bf16(k0, qf0, sA[n], 0, 0, 0);
            sA[n] = __builtin_amdgcn_mfma_f32_16x16x32_bf16(k1, qf1, sA[n], 0, 0, 0);
        }
#pragma unroll
        for (int n = 0; n < 4; ++n) {
            bf16x8 k0 = *(const bf16x8*)(lk1 + off[n][0]);
            bf16x8 k1 = *(const bf16x8*)(lk1 + off[n][1]);
            sB[n] = __builtin_amdgcn_mfma_f32_16x16x32_bf16(k0, qf0, sB[n], 0, 0, 0);
            sB[n] = __builtin_amdgcn_mfma_f32_16x16x32_bf16(k1, qf1, sB[n], 0, 0, 0);
        }
        __builtin_amdgcn_s_setprio(0);

        // ---- softmax numerator: raw exp2 (no max, no cross-lane), both halves ----
#pragma unroll
        for (int n = 0; n < 4; ++n)
#pragma unroll
            for (int j = 0; j < 4; ++j) {
                sA[n][j] = exp2f(sA[n][j]);
                sB[n][j] = exp2f(sB[n][j]);
            }

        // ---- pack P^T fragments (lane-local; k-order matches V columns) ----
        bf16x8 paA0, paB0, paA1, paB1;
#pragma unroll
        for (int j = 0; j < 4; ++j) {
            paA0[j]     = (__bf16)sA[0][j];
            paA0[j + 4] = (__bf16)sA[1][j];
            paB0[j]     = (__bf16)sA[2][j];
            paB0[j + 4] = (__bf16)sA[3][j];
            paA1[j]     = (__bf16)sB[0][j];
            paA1[j + 4] = (__bf16)sB[1][j];
            paB1[j]     = (__bf16)sB[2][j];
            paB1[j + 4] = (__bf16)sB[3][j];
        }

        // ---- PV + MFMA row-sum, both halves ----
        __builtin_amdgcn_s_setprio(1);
        lsum = __builtin_amdgcn_mfma_f32_16x16x32_bf16(ones, paA0, lsum, 0, 0, 0);
        lsum = __builtin_amdgcn_mfma_f32_16x16x32_bf16(ones, paB0, lsum, 0, 0, 0);
        lsum = __builtin_amdgcn_mfma_f32_16x16x32_bf16(ones, paA1, lsum, 0, 0, 0);
        lsum = __builtin_amdgcn_mfma_f32_16x16x32_bf16(ones, paB1, lsum, 0, 0, 0);
#pragma unroll
        for (int n2 = 0; n2 < 4; ++n2) {
            bf16x8 v0 = *(const bf16x8*)(lv0 + off[n2][0]);
            bf16x8 v1 = *(const bf16x8*)(lv0 + off[n2][1]);
            c[n2] = __builtin_amdgcn_mfma_f32_16x16x32_bf16(v0, paA0, c[n2], 0, 0, 0);
            c[n2] = __builtin_amdgcn_mfma_f32_16x16x32_bf16(v1, paB0, c[n2], 0, 0, 0);
            bf16x8 u0 = *(const bf16x8*)(lv1 + off[n2][0]);
            bf16x8 u1 = *(const bf16x8*)(lv1 + off[n2][1]);
            c[n2] = __builtin_amdgcn_mfma_f32_16x16x32_bf16(u0, paA1, c[n2], 0, 0, 0);
            c[n2] = __builtin_amdgcn_mfma_f32_16x16x32_bf16(u1, paB1, c[n2], 0, 0, 0);
        }
        __builtin_amdgcn_s_setprio(0);
    }

    // ---- write ctx (merged heads, bf16): [B, S, D], 8B vector stores ----
    const float inv = 1.0f / lsum[0];
    const int q = q0 + w * 16 + i15;
#pragma unroll
    for (int n2 = 0; n2 < 4; ++n2) {
        bf16x4 o;
#pragma unroll
        for (int j = 0; j < 4; ++j) o[j] = (__bf16)(c[n2][j] * inv);
        *(bf16x4*)(Cb + (size_t)(b * SDIM + q) * DDIM + h * HD + n2 * 16 + q4 * 4) = o;
    }
}

// ---------------------------------------------------------------------------
extern "C" void kernel_launch(void* const* d_in, const int* in_sizes, int n_in,
                              void* d_out, int out_size, void* d_ws, size_t ws_size,
                              hipStream_t stream) {
    const float* query = (const float*)d_in[0];
    const float* bank  = (const float*)d_in[1];
    const float* Wq = (const float*)d_in[2];
    const float* bq = (const float*)d_in[3];
    const float* Wk = (const float*)d_in[4];
    const float* bk = (const float*)d_in[5];
    const float* Wv = (const float*)d_in[6];
    const float* bv = (const float*)d_in[7];
    const float* Wo = (const float*)d_in[8];
    const float* bo = (const float*)d_in[9];
    float* out = (float*)d_out;

    char* ws = (char*)d_ws;
    __bf16* xq  = (__bf16*)(ws);                    // 8 MB  [4096,1024] (reused as ctx)
    __bf16* xkv = (__bf16*)(ws + (8u  << 20));      // 8 MB
    __bf16* wq  = (__bf16*)(ws + (16u << 20));      // 2 MB
    __bf16* wk  = (__bf16*)(ws + (18u << 20));      // 2 MB
    __bf16* wv  = (__bf16*)(ws + (20u << 20));      // 2 MB
    __bf16* wo  = (__bf16*)(ws + (22u << 20));      // 2 MB
    __bf16* qbuf = (__bf16*)(ws + (24u << 20));     // 8 MB [B,H,S,hd] (scaled)
    __bf16* kbuf = (__bf16*)(ws + (32u << 20));     // 8 MB [B,H,S,hd]
    __bf16* vtbuf = (__bf16*)(ws + (40u << 20));    // 8 MB [B,H,hd,S]
    __bf16* ctx = xq;                               // alias: xq dead after QKV gemm

    // fp32 -> bf16 (single launch for all 6 tensors)
    cvt_all<<<6144, 256, 0, stream>>>(query, bank, Wq, Wk, Wv, Wo,
                                      xq, xkv, wq, wk, wv, wo);

    // fused QKV projections — 768 blocks, XCD panel-clustered decode inside
    gemm_bt<0><<<768, 256, 0, stream>>>(
        xq, xkv, wq, wk, wv, bq, bk, bv, qbuf, kbuf, vtbuf, nullptr);

    // flash attention (1D grid, XCD head-clustering decode inside)
    attn_fwd<<<512, 512, 0, stream>>>(qbuf, kbuf, vtbuf, ctx);

    // output projection (fp32 out) — 512 blocks, XCD panel-clustered
    gemm_bt<2><<<512, 256, 0, stream>>>(
        ctx, nullptr, wo, nullptr, nullptr, bo, nullptr, nullptr,
        nullptr, nullptr, nullptr, out);
}

// Round 12
// 124.392 us; speedup vs baseline: 1.0989x; 1.0916x over previous
//
#include <hip/hip_runtime.h>

// ---------------------------------------------------------------------------
// MultiheadAttention: out = (softmax((Xq Wq^T + bq)(Xb Wk^T + bk)^T / 8) (Xb Wv^T + bv)) Wo^T + bo
// B=2, S=2048, D=1024, H=16, hd=64.  All GEMMs + attention in bf16 MFMA, fp32 accum.
// ---------------------------------------------------------------------------

#define BDIM   2
#define SDIM   2048
#define DDIM   1024
#define HEADS  16
#define HD     64
#define MROWS  (BDIM * SDIM)   // 4096

typedef float  f32x4  __attribute__((ext_vector_type(4)));
typedef __bf16 bf16x8 __attribute__((ext_vector_type(8)));
typedef __bf16 bf16x4 __attribute__((ext_vector_type(4)));

// Q scale: 1/sqrt(hd) * log2(e)  (softmax computed in exp2 domain)
#define QSCALE 0.18033688011112042f

__device__ __forceinline__ void stage16(const void* g, void* l) {
    // global -> LDS direct copy, 16B per lane, dest = wave-uniform base + lane*16
    __builtin_amdgcn_global_load_lds((const __attribute__((address_space(1))) void*)g,
                                     (__attribute__((address_space(3))) void*)l,
                                     16, 0, 0);
}

// ---------------------------------------------------------------------------
// ALL fp32 -> bf16 conversions in ONE launch.
// chunks: query 524288, bank 524288, then 4 weights x 131072 (8 floats each).
// ---------------------------------------------------------------------------
__global__ __launch_bounds__(256) void cvt_all(
    const float* __restrict__ q, const float* __restrict__ bank,
    const float* __restrict__ Wq, const float* __restrict__ Wk,
    const float* __restrict__ Wv, const float* __restrict__ Wo,
    __bf16* __restrict__ xq, __bf16* __restrict__ xkv,
    __bf16* __restrict__ wq, __bf16* __restrict__ wk,
    __bf16* __restrict__ wv, __bf16* __restrict__ wo) {
    const int i = blockIdx.x * 256 + threadIdx.x;   // 0..1572863
    const float* in;
    __bf16* out;
    int off;
    if (i < 524288)       { in = q;    out = xq;  off = i; }
    else if (i < 1048576) { in = bank; out = xkv; off = i - 524288; }
    else {
        const int j = i - 1048576;
        const int sel = j >> 17;
        off = j & 131071;
        in  = (sel == 0) ? Wq : (sel == 1) ? Wk : (sel == 2) ? Wv : Wo;
        out = (sel == 0) ? wq : (sel == 1) ? wk : (sel == 2) ? wv : wo;
    }
    const float4* p = (const float4*)in;
    float4 a = p[2 * off];
    float4 c = p[2 * off + 1];
    bf16x8 o;
    o[0] = (__bf16)a.x; o[1] = (__bf16)a.y; o[2] = (__bf16)a.z; o[3] = (__bf16)a.w;
    o[4] = (__bf16)c.x; o[5] = (__bf16)c.y; o[6] = (__bf16)c.z; o[7] = (__bf16)c.w;
    *(bf16x8*)(out + 8 * off) = o;
}

// ---------------------------------------------------------------------------
// B^T GEMM (round-9 proven body: BK=32, 16 KB LDS/operand, 2-barrier loop).
// GRID IS TRANSPOSED vs round 9: blockIdx.x = ROW-block (fastest), so with
// XCD = bid&7 each A row-panel is read by exactly ONE XCD (its col-blocks all
// land on the same XCD) -> A L2-fill ~190 MB -> ~24 MB; W-panels replicate
// across XCDs instead (2 MB each, cheap).  Same block count & occupancy.
// out[r][n] = sum_k A[r][k] * W[n][k] + bias.
// MODE 0: 128x128 tile, grid (32,8,3); z selects {Q,K,V}; bf16 head-split out
//         (V transposed [B,H,hd,S] via scatter epilogue).
// MODE 2: 128x64 tile, grid (32,16), fp32 out (2 blocks/CU tail launch).
// ---------------------------------------------------------------------------
template <int MODE>
__global__ __launch_bounds__(256) void gemm_bt(
    const __bf16* __restrict__ Aq, const __bf16* __restrict__ Akv,
    const __bf16* __restrict__ W0, const __bf16* __restrict__ W1,
    const __bf16* __restrict__ W2,
    const float* __restrict__ b0, const float* __restrict__ b1,
    const float* __restrict__ b2,
    __bf16* __restrict__ Qo, __bf16* __restrict__ Ko, __bf16* __restrict__ Vo,
    float* __restrict__ Fo) {
    constexpr int NF = (MODE == 2) ? 2 : 4;        // n-fragments per wave
    constexpr int NCOL = NF * 32;                  // block col-tile (64 or 128)
    __shared__ __align__(16) __bf16 ldsA[128 * 32];
    __shared__ __align__(16) __bf16 ldsB[(NCOL)*32];

    const int t = threadIdx.x;
    const int l = t & 63;
    const int w = t >> 6;
    const int z = (MODE == 0) ? (int)blockIdx.z : 0;

    const __bf16* A  = (MODE == 0 && z != 0) ? Akv : Aq;
    const __bf16* Wm = (z == 0) ? W0 : (z == 1 ? W1 : W2);
    const float*  bias = (z == 0) ? b0 : (z == 1 ? b1 : b2);

    const int row0 = blockIdx.x * 128;    // row-block fastest -> XCD-local A panel
    const int col0 = blockIdx.y * NCOL;

    const __bf16* ga = A  + (size_t)(row0 + (t >> 2)) * DDIM + (t & 3) * 8;
    const __bf16* gb = Wm + (size_t)(col0 + (t >> 2)) * DDIM + (t & 3) * 8;
    __bf16* la = ldsA + (t & ~63) * 8;  // wave-uniform base
    __bf16* lb = ldsB + (t & ~63) * 8;

    const int wm = w >> 1, wn = w & 1;
    const int aoff = (wm * 64 + (l & 15)) * 32 + (l >> 4) * 8;
    const int boff = (wn * (NF * 16) + (l & 15)) * 32 + (l >> 4) * 8;

    f32x4 acc[4][NF] = {};

    for (int kb = 0; kb < DDIM; kb += 32) {
        __syncthreads();
        stage16(ga + kb,             la);
        stage16(ga + kb + 64 * DDIM, la + 2048);
        stage16(gb + kb,             lb);
        if constexpr (MODE == 0)
            stage16(gb + kb + 64 * DDIM, lb + 2048);
        __syncthreads();

        bf16x8 af[4], bf[NF];
#pragma unroll
        for (int m = 0; m < 4; ++m) af[m] = *(const bf16x8*)(ldsA + aoff + m * 16 * 32);
#pragma unroll
        for (int n = 0; n < NF; ++n) bf[n] = *(const bf16x8*)(ldsB + boff + n * 16 * 32);
#pragma unroll
        for (int m = 0; m < 4; ++m)
#pragma unroll
            for (int n = 0; n < NF; ++n)
                acc[m][n] = __builtin_amdgcn_mfma_f32_16x16x32_bf16(af[m], bf[n], acc[m][n], 0, 0, 0);
    }

    // ---- epilogue: C/D layout col = lane&15, row = (lane>>4)*4 + j ----
#pragma unroll
    for (int m = 0; m < 4; ++m) {
        const int rbase = row0 + wm * 64 + m * 16 + (l >> 4) * 4;
#pragma unroll
        for (int n = 0; n < NF; ++n) {
            const int col = col0 + wn * (NF * 16) + n * 16 + (l & 15);
            const float bv = bias[col];
            if constexpr (MODE == 0) {
                const int hh = col >> 6, dd = col & 63;
#pragma unroll
                for (int j = 0; j < 4; ++j) {
                    const int r = rbase + j;
                    const int b = r >> 11, s = r & 2047;
                    const float v = acc[m][n][j] + bv;
                    if (z == 0) {
                        Qo[(((b * HEADS + hh) * SDIM + s) << 6) + dd] = (__bf16)(v * QSCALE);
                    } else if (z == 1) {
                        Ko[(((b * HEADS + hh) * SDIM + s) << 6) + dd] = (__bf16)v;
                    } else {  // V stored transposed: [B,H,hd,S]
                        Vo[(((b * HEADS + hh) * HD + dd) << 11) + s] = (__bf16)v;
                    }
                }
            } else {
#pragma unroll
                for (int j = 0; j < 4; ++j) {
                    Fo[(size_t)(rbase + j) * DDIM + col] = acc[m][n][j] + bv;
                }
            }
        }
    }
}

// ---------------------------------------------------------------------------
// Flash attention v7b (unchanged): 512 blocks x 512 threads = 8 waves x 16
// q-rows, KVBLK=128, XCD head-clustering, swapped QK^T + sigma-permuted K
// staging, XOR-swizzled LDS, no-max exp2 softmax, row-sum on the MFMA pipe.
// ---------------------------------------------------------------------------
__global__ __launch_bounds__(512) void attn_fwd(const __bf16* __restrict__ Qb,
                                                const __bf16* __restrict__ Kb,
                                                const __bf16* __restrict__ Vtb,
                                                __bf16* __restrict__ Cb) {
    __shared__ __align__(16) __bf16 ldsK[2][2][64 * 64];
    __shared__ __align__(16) __bf16 ldsV[2][2][64 * 64];

    const int t = threadIdx.x;        // 0..511
    const int l = t & 63;
    const int w = t >> 6;             // 0..7
    const int i15 = l & 15;
    const int q4 = l >> 4;

    // --- XCD head-clustering decode (bijective on 512 blocks) ---
    const int bid  = blockIdx.x;
    const int xcd  = bid & 7;
    const int wloc = bid >> 3;               // 0..63 within XCD
    const int bh   = xcd * 4 + (wloc >> 4);  // 4 (b,h) pairs per XCD
    const int qb   = wloc & 15;              // q-block within head (consecutive)
    const int b    = bh >> 4;
    const int h    = bh & 15;
    const size_t base = (size_t)bh * SDIM * HD;
    const int q0 = qb * 128;

    // Q fragments (B-operand of swapped QK^T): col=q=i15, k-dim=d
    const __bf16* qp = Qb + base + (size_t)(q0 + w * 16 + i15) * HD + q4 * 8;
    const bf16x8 qf0 = *(const bf16x8*)(qp);
    const bf16x8 qf1 = *(const bf16x8*)(qp + 32);

    // --- staging source addresses (rule 21: linear LDS dest, permuted source)
    const int r0 = t >> 3;                    // LDS row this thread fills
    const int sl = (t & 7) ^ (r0 & 7);        // source slot = phys slot ^ row&7
    const int sig0 = ((r0 >> 5) << 5) | (((r0 >> 2) & 3) << 3)
                   | (((r0 >> 4) & 1) << 2) | (r0 & 3);      // sigma-permuted K row
    const __bf16* gk = Kb  + base + (size_t)sig0 * HD + sl * 8;
    const __bf16* gv = Vtb + base + (size_t)r0 * SDIM + sl * 8;
    const int wb = (t & ~63) * 8;             // wave-uniform LDS element base

    // --- swizzled read offsets (elements), same table for K and V reads ---
    const int xr = i15 & 7;
    int off[4][2];
#pragma unroll
    for (int n = 0; n < 4; ++n)
#pragma unroll
        for (int hh = 0; hh < 2; ++hh)
            off[n][hh] = (n * 16 + i15) * 64 + (((hh * 4 + q4) ^ xr) << 3);

    // ones fragment for the MFMA row-sum
    bf16x8 ones;
#pragma unroll
    for (int j = 0; j < 8; ++j) ones[j] = (__bf16)1.0f;

    f32x4 c[4] = {};
    f32x4 lsum = {};

    // prologue: stage round 0 (two 64-row sub-tiles of K and V) into buffer 0
    stage16(gk,           &ldsK[0][0][wb]);
    stage16(gk + 64 * HD, &ldsK[0][1][wb]);
    stage16(gv,           &ldsV[0][0][wb]);
    stage16(gv + 64,      &ldsV[0][1][wb]);

#pragma unroll 2
    for (int r = 0; r < SDIM / 128; ++r) {
        const int bb = r & 1;
        __syncthreads();   // buf[bb] staged & prev compute on buf[bb^1] done

        if (r + 1 < SDIM / 128) {
            const int s0 = (r + 1) * 128;
            stage16(gk + (size_t)s0 * HD,        &ldsK[bb ^ 1][0][wb]);
            stage16(gk + (size_t)(s0 + 64) * HD, &ldsK[bb ^ 1][1][wb]);
            stage16(gv + s0,                     &ldsV[bb ^ 1][0][wb]);
            stage16(gv + s0 + 64,                &ldsV[bb ^ 1][1][wb]);
        }

        const __bf16* lk0 = &ldsK[bb][0][0];
        const __bf16* lk1 = &ldsK[bb][1][0];
        const __bf16* lv0 = &ldsV[bb][0][0];
        const __bf16* lv1 = &ldsV[bb][1][0];

        // ---- QK^T (swapped), both halves: sA/sB hold S^T[k-block n][q] ----
        f32x4 sA[4] = {}, sB[4] = {};
        __builtin_amdgcn_s_setprio(1);
#pragma unroll
        for (int n = 0; n < 4; ++n) {
            bf16x8 k0 = *(const bf16x8*)(lk0 + off[n][0]);
            bf16x8 k1 = *(const bf16x8*)(lk0 + off[n][1]);
            sA[n] = __builtin_amdgcn_mfma_f32_16x16x32_bf16(k0, qf0, sA[n], 0, 0, 0);
            sA[n] = __builtin_amdgcn_mfma_f32_16x16x32_bf16(k1, qf1, sA[n], 0, 0, 0);
        }
#pragma unroll
        for (int n = 0; n < 4; ++n) {
            bf16x8 k0 = *(const bf16x8*)(lk1 + off[n][0]);
            bf16x8 k1 = *(const bf16x8*)(lk1 + off[n][1]);
            sB[n] = __builtin_amdgcn_mfma_f32_16x16x32_bf16(k0, qf0, sB[n], 0, 0, 0);
            sB[n] = __builtin_amdgcn_mfma_f32_16x16x32_bf16(k1, qf1, sB[n], 0, 0, 0);
        }
        __builtin_amdgcn_s_setprio(0);

        // ---- softmax numerator: raw exp2 (no max, no cross-lane), both halves ----
#pragma unroll
        for (int n = 0; n < 4; ++n)
#pragma unroll
            for (int j = 0; j < 4; ++j) {
                sA[n][j] = exp2f(sA[n][j]);
                sB[n][j] = exp2f(sB[n][j]);
            }

        // ---- pack P^T fragments (lane-local; k-order matches V columns) ----
        bf16x8 paA0, paB0, paA1, paB1;
#pragma unroll
        for (int j = 0; j < 4; ++j) {
            paA0[j]     = (__bf16)sA[0][j];
            paA0[j + 4] = (__bf16)sA[1][j];
            paB0[j]     = (__bf16)sA[2][j];
            paB0[j + 4] = (__bf16)sA[3][j];
            paA1[j]     = (__bf16)sB[0][j];
            paA1[j + 4] = (__bf16)sB[1][j];
            paB1[j]     = (__bf16)sB[2][j];
            paB1[j + 4] = (__bf16)sB[3][j];
        }

        // ---- PV + MFMA row-sum, both halves ----
        __builtin_amdgcn_s_setprio(1);
        lsum = __builtin_amdgcn_mfma_f32_16x16x32_bf16(ones, paA0, lsum, 0, 0, 0);
        lsum = __builtin_amdgcn_mfma_f32_16x16x32_bf16(ones, paB0, lsum, 0, 0, 0);
        lsum = __builtin_amdgcn_mfma_f32_16x16x32_bf16(ones, paA1, lsum, 0, 0, 0);
        lsum = __builtin_amdgcn_mfma_f32_16x16x32_bf16(ones, paB1, lsum, 0, 0, 0);
#pragma unroll
        for (int n2 = 0; n2 < 4; ++n2) {
            bf16x8 v0 = *(const bf16x8*)(lv0 + off[n2][0]);
            bf16x8 v1 = *(const bf16x8*)(lv0 + off[n2][1]);
            c[n2] = __builtin_amdgcn_mfma_f32_16x16x32_bf16(v0, paA0, c[n2], 0, 0, 0);
            c[n2] = __builtin_amdgcn_mfma_f32_16x16x32_bf16(v1, paB0, c[n2], 0, 0, 0);
            bf16x8 u0 = *(const bf16x8*)(lv1 + off[n2][0]);
            bf16x8 u1 = *(const bf16x8*)(lv1 + off[n2][1]);
            c[n2] = __builtin_amdgcn_mfma_f32_16x16x32_bf16(u0, paA1, c[n2], 0, 0, 0);
            c[n2] = __builtin_amdgcn_mfma_f32_16x16x32_bf16(u1, paB1, c[n2], 0, 0, 0);
        }
        __builtin_amdgcn_s_setprio(0);
    }

    // ---- write ctx (merged heads, bf16): [B, S, D], 8B vector stores ----
    const float inv = 1.0f / lsum[0];
    const int q = q0 + w * 16 + i15;
#pragma unroll
    for (int n2 = 0; n2 < 4; ++n2) {
        bf16x4 o;
#pragma unroll
        for (int j = 0; j < 4; ++j) o[j] = (__bf16)(c[n2][j] * inv);
        *(bf16x4*)(Cb + (size_t)(b * SDIM + q) * DDIM + h * HD + n2 * 16 + q4 * 4) = o;
    }
}

// ---------------------------------------------------------------------------
extern "C" void kernel_launch(void* const* d_in, const int* in_sizes, int n_in,
                              void* d_out, int out_size, void* d_ws, size_t ws_size,
                              hipStream_t stream) {
    const float* query = (const float*)d_in[0];
    const float* bank  = (const float*)d_in[1];
    const float* Wq = (const float*)d_in[2];
    const float* bq = (const float*)d_in[3];
    const float* Wk = (const float*)d_in[4];
    const float* bk = (const float*)d_in[5];
    const float* Wv = (const float*)d_in[6];
    const float* bv = (const float*)d_in[7];
    const float* Wo = (const float*)d_in[8];
    const float* bo = (const float*)d_in[9];
    float* out = (float*)d_out;

    char* ws = (char*)d_ws;
    __bf16* xq  = (__bf16*)(ws);                    // 8 MB  [4096,1024] (reused as ctx)
    __bf16* xkv = (__bf16*)(ws + (8u  << 20));      // 8 MB
    __bf16* wq  = (__bf16*)(ws + (16u << 20));      // 2 MB
    __bf16* wk  = (__bf16*)(ws + (18u << 20));      // 2 MB
    __bf16* wv  = (__bf16*)(ws + (20u << 20));      // 2 MB
    __bf16* wo  = (__bf16*)(ws + (22u << 20));      // 2 MB
    __bf16* qbuf = (__bf16*)(ws + (24u << 20));     // 8 MB [B,H,S,hd] (scaled)
    __bf16* kbuf = (__bf16*)(ws + (32u << 20));     // 8 MB [B,H,S,hd]
    __bf16* vtbuf = (__bf16*)(ws + (40u << 20));    // 8 MB [B,H,hd,S]
    __bf16* ctx = xq;                               // alias: xq dead after QKV gemm

    // fp32 -> bf16 (single launch for all 6 tensors)
    cvt_all<<<6144, 256, 0, stream>>>(query, bank, Wq, Wk, Wv, Wo,
                                      xq, xkv, wq, wk, wv, wo);

    // fused QKV projections — row-block-fastest grid (A-panel XCD locality)
    gemm_bt<0><<<dim3(32, 8, 3), 256, 0, stream>>>(
        xq, xkv, wq, wk, wv, bq, bk, bv, qbuf, kbuf, vtbuf, nullptr);

    // flash attention (1D grid, XCD head-clustering decode inside)
    attn_fwd<<<512, 512, 0, stream>>>(qbuf, kbuf, vtbuf, ctx);

    // output projection (fp32 out) — row-block-fastest grid
    gemm_bt<2><<<dim3(32, 16, 1), 256, 0, stream>>>(
        ctx, nullptr, wo, nullptr, nullptr, bo, nullptr, nullptr,
        nullptr, nullptr, nullptr, out);
}

// Round 13
// 113.894 us; speedup vs baseline: 1.2002x; 1.0922x over previous
//
#include <hip/hip_runtime.h>

// ---------------------------------------------------------------------------
// MultiheadAttention: out = (softmax((Xq Wq^T + bq)(Xb Wk^T + bk)^T / 8) (Xb Wv^T + bv)) Wo^T + bo
// B=2, S=2048, D=1024, H=16, hd=64.  All GEMMs + attention in bf16 MFMA, fp32 accum.
// ---------------------------------------------------------------------------

#define BDIM   2
#define SDIM   2048
#define DDIM   1024
#define HEADS  16
#define HD     64
#define MROWS  (BDIM * SDIM)   // 4096

typedef float  f32x4  __attribute__((ext_vector_type(4)));
typedef __bf16 bf16x8 __attribute__((ext_vector_type(8)));
typedef __bf16 bf16x4 __attribute__((ext_vector_type(4)));
typedef unsigned u32x4 __attribute__((ext_vector_type(4)));

// Q scale: 1/sqrt(hd) * log2(e)  (softmax computed in exp2 domain)
#define QSCALE 0.18033688011112042f

__device__ __forceinline__ void stage16(const void* g, void* l) {
    // global -> LDS direct copy, 16B per lane, dest = wave-uniform base + lane*16
    __builtin_amdgcn_global_load_lds((const __attribute__((address_space(1))) void*)g,
                                     (__attribute__((address_space(3))) void*)l,
                                     16, 0, 0);
}

// exact single-instruction softmax data path (theory R13: hipcc lowers
// (__bf16)f casts + element inserts to ~7-14 VALU ops/score; these are 1-1.5)
__device__ __forceinline__ float vexp2(float x) {
    float r;
    asm("v_exp_f32 %0, %1" : "=v"(r) : "v"(x));
    return r;
}
__device__ __forceinline__ unsigned pk2(float lo, float hi) {
    unsigned r;
    asm("v_cvt_pk_bf16_f32 %0, %1, %2" : "=v"(r) : "v"(lo), "v"(hi));
    return r;
}

// ---------------------------------------------------------------------------
// ALL fp32 -> bf16 conversions in ONE launch.
// chunks: query 524288, bank 524288, then 4 weights x 131072 (8 floats each).
// ---------------------------------------------------------------------------
__global__ __launch_bounds__(256) void cvt_all(
    const float* __restrict__ q, const float* __restrict__ bank,
    const float* __restrict__ Wq, const float* __restrict__ Wk,
    const float* __restrict__ Wv, const float* __restrict__ Wo,
    __bf16* __restrict__ xq, __bf16* __restrict__ xkv,
    __bf16* __restrict__ wq, __bf16* __restrict__ wk,
    __bf16* __restrict__ wv, __bf16* __restrict__ wo) {
    const int i = blockIdx.x * 256 + threadIdx.x;   // 0..1572863
    const float* in;
    __bf16* out;
    int off;
    if (i < 524288)       { in = q;    out = xq;  off = i; }
    else if (i < 1048576) { in = bank; out = xkv; off = i - 524288; }
    else {
        const int j = i - 1048576;
        const int sel = j >> 17;
        off = j & 131071;
        in  = (sel == 0) ? Wq : (sel == 1) ? Wk : (sel == 2) ? Wv : Wo;
        out = (sel == 0) ? wq : (sel == 1) ? wk : (sel == 2) ? wv : wo;
    }
    const float4* p = (const float4*)in;
    float4 a = p[2 * off];
    float4 c = p[2 * off + 1];
    bf16x8 o;
    o[0] = (__bf16)a.x; o[1] = (__bf16)a.y; o[2] = (__bf16)a.z; o[3] = (__bf16)a.w;
    o[4] = (__bf16)c.x; o[5] = (__bf16)c.y; o[6] = (__bf16)c.z; o[7] = (__bf16)c.w;
    *(bf16x8*)(out + 8 * off) = o;
}

// ---------------------------------------------------------------------------
// B^T GEMM (round-9 body: BK=32, 16 KB LDS/operand, 2-barrier loop), grid
// transposed (round-12 win): blockIdx.x = ROW-block (fastest) -> with XCD =
// bid&7 each A row-panel is read by exactly ONE XCD.
// out[r][n] = sum_k A[r][k] * W[n][k] + bias.
// MODE 0: 128x128 tile, grid (32,8,3); z selects {Q,K,V}; bf16 head-split out
//         (V transposed [B,H,hd,S] via scatter epilogue).
// MODE 2: 128x64 tile, grid (32,16), fp32 out (2 blocks/CU tail launch).
// ---------------------------------------------------------------------------
template <int MODE>
__global__ __launch_bounds__(256) void gemm_bt(
    const __bf16* __restrict__ Aq, const __bf16* __restrict__ Akv,
    const __bf16* __restrict__ W0, const __bf16* __restrict__ W1,
    const __bf16* __restrict__ W2,
    const float* __restrict__ b0, const float* __restrict__ b1,
    const float* __restrict__ b2,
    __bf16* __restrict__ Qo, __bf16* __restrict__ Ko, __bf16* __restrict__ Vo,
    float* __restrict__ Fo) {
    constexpr int NF = (MODE == 2) ? 2 : 4;        // n-fragments per wave
    constexpr int NCOL = NF * 32;                  // block col-tile (64 or 128)
    __shared__ __align__(16) __bf16 ldsA[128 * 32];
    __shared__ __align__(16) __bf16 ldsB[(NCOL)*32];

    const int t = threadIdx.x;
    const int l = t & 63;
    const int w = t >> 6;
    const int z = (MODE == 0) ? (int)blockIdx.z : 0;

    const __bf16* A  = (MODE == 0 && z != 0) ? Akv : Aq;
    const __bf16* Wm = (z == 0) ? W0 : (z == 1 ? W1 : W2);
    const float*  bias = (z == 0) ? b0 : (z == 1 ? b1 : b2);

    const int row0 = blockIdx.x * 128;    // row-block fastest -> XCD-local A panel
    const int col0 = blockIdx.y * NCOL;

    const __bf16* ga = A  + (size_t)(row0 + (t >> 2)) * DDIM + (t & 3) * 8;
    const __bf16* gb = Wm + (size_t)(col0 + (t >> 2)) * DDIM + (t & 3) * 8;
    __bf16* la = ldsA + (t & ~63) * 8;  // wave-uniform base
    __bf16* lb = ldsB + (t & ~63) * 8;

    const int wm = w >> 1, wn = w & 1;
    const int aoff = (wm * 64 + (l & 15)) * 32 + (l >> 4) * 8;
    const int boff = (wn * (NF * 16) + (l & 15)) * 32 + (l >> 4) * 8;

    f32x4 acc[4][NF] = {};

    for (int kb = 0; kb < DDIM; kb += 32) {
        __syncthreads();
        stage16(ga + kb,             la);
        stage16(ga + kb + 64 * DDIM, la + 2048);
        stage16(gb + kb,             lb);
        if constexpr (MODE == 0)
            stage16(gb + kb + 64 * DDIM, lb + 2048);
        __syncthreads();

        bf16x8 af[4], bf[NF];
#pragma unroll
        for (int m = 0; m < 4; ++m) af[m] = *(const bf16x8*)(ldsA + aoff + m * 16 * 32);
#pragma unroll
        for (int n = 0; n < NF; ++n) bf[n] = *(const bf16x8*)(ldsB + boff + n * 16 * 32);
#pragma unroll
        for (int m = 0; m < 4; ++m)
#pragma unroll
            for (int n = 0; n < NF; ++n)
                acc[m][n] = __builtin_amdgcn_mfma_f32_16x16x32_bf16(af[m], bf[n], acc[m][n], 0, 0, 0);
    }

    // ---- epilogue: C/D layout col = lane&15, row = (lane>>4)*4 + j ----
#pragma unroll
    for (int m = 0; m < 4; ++m) {
        const int rbase = row0 + wm * 64 + m * 16 + (l >> 4) * 4;
#pragma unroll
        for (int n = 0; n < NF; ++n) {
            const int col = col0 + wn * (NF * 16) + n * 16 + (l & 15);
            const float bv = bias[col];
            if constexpr (MODE == 0) {
                const int hh = col >> 6, dd = col & 63;
#pragma unroll
                for (int j = 0; j < 4; ++j) {
                    const int r = rbase + j;
                    const int b = r >> 11, s = r & 2047;
                    const float v = acc[m][n][j] + bv;
                    if (z == 0) {
                        Qo[(((b * HEADS + hh) * SDIM + s) << 6) + dd] = (__bf16)(v * QSCALE);
                    } else if (z == 1) {
                        Ko[(((b * HEADS + hh) * SDIM + s) << 6) + dd] = (__bf16)v;
                    } else {  // V stored transposed: [B,H,hd,S]
                        Vo[(((b * HEADS + hh) * HD + dd) << 11) + s] = (__bf16)v;
                    }
                }
            } else {
#pragma unroll
                for (int j = 0; j < 4; ++j) {
                    Fo[(size_t)(rbase + j) * DDIM + col] = acc[m][n][j] + bv;
                }
            }
        }
    }
}

// ---------------------------------------------------------------------------
// Flash attention v8: v7b structure (512 blocks x 512 threads, KVBLK=128,
// XCD head-clustering, swapped QK^T + sigma-permuted K staging, XOR-swizzled
// LDS, no-max softmax, MFMA row-sum) with the softmax numerator data path
// reduced to exact single instructions: v_exp_f32 per score +
// v_cvt_pk_bf16_f32 per score-pair building the packed P fragments directly.
// ---------------------------------------------------------------------------
__global__ __launch_bounds__(512) void attn_fwd(const __bf16* __restrict__ Qb,
                                                const __bf16* __restrict__ Kb,
                                                const __bf16* __restrict__ Vtb,
                                                __bf16* __restrict__ Cb) {
    __shared__ __align__(16) __bf16 ldsK[2][2][64 * 64];
    __shared__ __align__(16) __bf16 ldsV[2][2][64 * 64];

    const int t = threadIdx.x;        // 0..511
    const int l = t & 63;
    const int w = t >> 6;             // 0..7
    const int i15 = l & 15;
    const int q4 = l >> 4;

    // --- XCD head-clustering decode (bijective on 512 blocks) ---
    const int bid  = blockIdx.x;
    const int xcd  = bid & 7;
    const int wloc = bid >> 3;               // 0..63 within XCD
    const int bh   = xcd * 4 + (wloc >> 4);  // 4 (b,h) pairs per XCD
    const int qb   = wloc & 15;              // q-block within head (consecutive)
    const int b    = bh >> 4;
    const int h    = bh & 15;
    const size_t base = (size_t)bh * SDIM * HD;
    const int q0 = qb * 128;

    // Q fragments (B-operand of swapped QK^T): col=q=i15, k-dim=d
    const __bf16* qp = Qb + base + (size_t)(q0 + w * 16 + i15) * HD + q4 * 8;
    const bf16x8 qf0 = *(const bf16x8*)(qp);
    const bf16x8 qf1 = *(const bf16x8*)(qp + 32);

    // --- staging source addresses (rule 21: linear LDS dest, permuted source)
    const int r0 = t >> 3;                    // LDS row this thread fills
    const int sl = (t & 7) ^ (r0 & 7);        // source slot = phys slot ^ row&7
    const int sig0 = ((r0 >> 5) << 5) | (((r0 >> 2) & 3) << 3)
                   | (((r0 >> 4) & 1) << 2) | (r0 & 3);      // sigma-permuted K row
    const __bf16* gk = Kb  + base + (size_t)sig0 * HD + sl * 8;
    const __bf16* gv = Vtb + base + (size_t)r0 * SDIM + sl * 8;
    const int wb = (t & ~63) * 8;             // wave-uniform LDS element base

    // --- swizzled read offsets (elements), same table for K and V reads ---
    const int xr = i15 & 7;
    int off[4][2];
#pragma unroll
    for (int n = 0; n < 4; ++n)
#pragma unroll
        for (int hh = 0; hh < 2; ++hh)
            off[n][hh] = (n * 16 + i15) * 64 + (((hh * 4 + q4) ^ xr) << 3);

    // ones fragment for the MFMA row-sum
    bf16x8 ones;
#pragma unroll
    for (int j = 0; j < 8; ++j) ones[j] = (__bf16)1.0f;

    f32x4 c[4] = {};
    f32x4 lsum = {};

    // prologue: stage round 0 (two 64-row sub-tiles of K and V) into buffer 0
    stage16(gk,           &ldsK[0][0][wb]);
    stage16(gk + 64 * HD, &ldsK[0][1][wb]);
    stage16(gv,           &ldsV[0][0][wb]);
    stage16(gv + 64,      &ldsV[0][1][wb]);

#pragma unroll 2
    for (int r = 0; r < SDIM / 128; ++r) {
        const int bb = r & 1;
        __syncthreads();   // buf[bb] staged & prev compute on buf[bb^1] done

        if (r + 1 < SDIM / 128) {
            const int s0 = (r + 1) * 128;
            stage16(gk + (size_t)s0 * HD,        &ldsK[bb ^ 1][0][wb]);
            stage16(gk + (size_t)(s0 + 64) * HD, &ldsK[bb ^ 1][1][wb]);
            stage16(gv + s0,                     &ldsV[bb ^ 1][0][wb]);
            stage16(gv + s0 + 64,                &ldsV[bb ^ 1][1][wb]);
        }

        const __bf16* lk0 = &ldsK[bb][0][0];
        const __bf16* lk1 = &ldsK[bb][1][0];
        const __bf16* lv0 = &ldsV[bb][0][0];
        const __bf16* lv1 = &ldsV[bb][1][0];

        // ---- QK^T (swapped), both halves: sA/sB hold S^T[k-block n][q] ----
        f32x4 sA[4] = {}, sB[4] = {};
        __builtin_amdgcn_s_setprio(1);
#pragma unroll
        for (int n = 0; n < 4; ++n) {
            bf16x8 k0 = *(const bf16x8*)(lk0 + off[n][0]);
            bf16x8 k1 = *(const bf16x8*)(lk0 + off[n][1]);
            sA[n] = __builtin_amdgcn_mfma_f32_16x16x32_bf16(k0, qf0, sA[n], 0, 0, 0);
            sA[n] = __builtin_amdgcn_mfma_f32_16x16x32_bf16(k1, qf1, sA[n], 0, 0, 0);
        }
#pragma unroll
        for (int n = 0; n < 4; ++n) {
            bf16x8 k0 = *(const bf16x8*)(lk1 + off[n][0]);
            bf16x8 k1 = *(const bf16x8*)(lk1 + off[n][1]);
            sB[n] = __builtin_amdgcn_mfma_f32_16x16x32_bf16(k0, qf0, sB[n], 0, 0, 0);
            sB[n] = __builtin_amdgcn_mfma_f32_16x16x32_bf16(k1, qf1, sB[n], 0, 0, 0);
        }
        __builtin_amdgcn_s_setprio(0);

        // ---- softmax numerator: v_exp_f32 per score (exact exp2), then
        //      v_cvt_pk_bf16_f32 per pair -> packed P^T fragments directly ----
#pragma unroll
        for (int n = 0; n < 4; ++n)
#pragma unroll
            for (int j = 0; j < 4; ++j) {
                sA[n][j] = vexp2(sA[n][j]);
                sB[n][j] = vexp2(sB[n][j]);
            }

        u32x4 pw0, pw1, pw2, pw3;
        pw0[0] = pk2(sA[0][0], sA[0][1]); pw0[1] = pk2(sA[0][2], sA[0][3]);
        pw0[2] = pk2(sA[1][0], sA[1][1]); pw0[3] = pk2(sA[1][2], sA[1][3]);
        pw1[0] = pk2(sA[2][0], sA[2][1]); pw1[1] = pk2(sA[2][2], sA[2][3]);
        pw1[2] = pk2(sA[3][0], sA[3][1]); pw1[3] = pk2(sA[3][2], sA[3][3]);
        pw2[0] = pk2(sB[0][0], sB[0][1]); pw2[1] = pk2(sB[0][2], sB[0][3]);
        pw2[2] = pk2(sB[1][0], sB[1][1]); pw2[3] = pk2(sB[1][2], sB[1][3]);
        pw3[0] = pk2(sB[2][0], sB[2][1]); pw3[1] = pk2(sB[2][2], sB[2][3]);
        pw3[2] = pk2(sB[3][0], sB[3][1]); pw3[3] = pk2(sB[3][2], sB[3][3]);
        const bf16x8 paA0 = __builtin_bit_cast(bf16x8, pw0);
        const bf16x8 paB0 = __builtin_bit_cast(bf16x8, pw1);
        const bf16x8 paA1 = __builtin_bit_cast(bf16x8, pw2);
        const bf16x8 paB1 = __builtin_bit_cast(bf16x8, pw3);

        // ---- PV + MFMA row-sum, both halves ----
        __builtin_amdgcn_s_setprio(1);
        lsum = __builtin_amdgcn_mfma_f32_16x16x32_bf16(ones, paA0, lsum, 0, 0, 0);
        lsum = __builtin_amdgcn_mfma_f32_16x16x32_bf16(ones, paB0, lsum, 0, 0, 0);
        lsum = __builtin_amdgcn_mfma_f32_16x16x32_bf16(ones, paA1, lsum, 0, 0, 0);
        lsum = __builtin_amdgcn_mfma_f32_16x16x32_bf16(ones, paB1, lsum, 0, 0, 0);
#pragma unroll
        for (int n2 = 0; n2 < 4; ++n2) {
            bf16x8 v0 = *(const bf16x8*)(lv0 + off[n2][0]);
            bf16x8 v1 = *(const bf16x8*)(lv0 + off[n2][1]);
            c[n2] = __builtin_amdgcn_mfma_f32_16x16x32_bf16(v0, paA0, c[n2], 0, 0, 0);
            c[n2] = __builtin_amdgcn_mfma_f32_16x16x32_bf16(v1, paB0, c[n2], 0, 0, 0);
            bf16x8 u0 = *(const bf16x8*)(lv1 + off[n2][0]);
            bf16x8 u1 = *(const bf16x8*)(lv1 + off[n2][1]);
            c[n2] = __builtin_amdgcn_mfma_f32_16x16x32_bf16(u0, paA1, c[n2], 0, 0, 0);
            c[n2] = __builtin_amdgcn_mfma_f32_16x16x32_bf16(u1, paB1, c[n2], 0, 0, 0);
        }
        __builtin_amdgcn_s_setprio(0);
    }

    // ---- write ctx (merged heads, bf16): [B, S, D], 8B vector stores ----
    const float inv = 1.0f / lsum[0];
    const int q = q0 + w * 16 + i15;
#pragma unroll
    for (int n2 = 0; n2 < 4; ++n2) {
        bf16x4 o;
#pragma unroll
        for (int j = 0; j < 4; ++j) o[j] = (__bf16)(c[n2][j] * inv);
        *(bf16x4*)(Cb + (size_t)(b * SDIM + q) * DDIM + h * HD + n2 * 16 + q4 * 4) = o;
    }
}

// ---------------------------------------------------------------------------
extern "C" void kernel_launch(void* const* d_in, const int* in_sizes, int n_in,
                              void* d_out, int out_size, void* d_ws, size_t ws_size,
                              hipStream_t stream) {
    const float* query = (const float*)d_in[0];
    const float* bank  = (const float*)d_in[1];
    const float* Wq = (const float*)d_in[2];
    const float* bq = (const float*)d_in[3];
    const float* Wk = (const float*)d_in[4];
    const float* bk = (const float*)d_in[5];
    const float* Wv = (const float*)d_in[6];
    const float* bv = (const float*)d_in[7];
    const float* Wo = (const float*)d_in[8];
    const float* bo = (const float*)d_in[9];
    float* out = (float*)d_out;

    char* ws = (char*)d_ws;
    __bf16* xq  = (__bf16*)(ws);                    // 8 MB  [4096,1024] (reused as ctx)
    __bf16* xkv = (__bf16*)(ws + (8u  << 20));      // 8 MB
    __bf16* wq  = (__bf16*)(ws + (16u << 20));      // 2 MB
    __bf16* wk  = (__bf16*)(ws + (18u << 20));      // 2 MB
    __bf16* wv  = (__bf16*)(ws + (20u << 20));      // 2 MB
    __bf16* wo  = (__bf16*)(ws + (22u << 20));      // 2 MB
    __bf16* qbuf = (__bf16*)(ws + (24u << 20));     // 8 MB [B,H,S,hd] (scaled)
    __bf16* kbuf = (__bf16*)(ws + (32u << 20));     // 8 MB [B,H,S,hd]
    __bf16* vtbuf = (__bf16*)(ws + (40u << 20));    // 8 MB [B,H,hd,S]
    __bf16* ctx = xq;                               // alias: xq dead after QKV gemm

    // fp32 -> bf16 (single launch for all 6 tensors)
    cvt_all<<<6144, 256, 0, stream>>>(query, bank, Wq, Wk, Wv, Wo,
                                      xq, xkv, wq, wk, wv, wo);

    // fused QKV projections — row-block-fastest grid (A-panel XCD locality)
    gemm_bt<0><<<dim3(32, 8, 3), 256, 0, stream>>>(
        xq, xkv, wq, wk, wv, bq, bk, bv, qbuf, kbuf, vtbuf, nullptr);

    // flash attention (1D grid, XCD head-clustering decode inside)
    attn_fwd<<<512, 512, 0, stream>>>(qbuf, kbuf, vtbuf, ctx);

    // output projection (fp32 out) — row-block-fastest grid
    gemm_bt<2><<<dim3(32, 16, 1), 256, 0, stream>>>(
        ctx, nullptr, wo, nullptr, nullptr, bo, nullptr, nullptr,
        nullptr, nullptr, nullptr, out);
}

// Round 14
// 112.365 us; speedup vs baseline: 1.2166x; 1.0136x over previous
//
#include <hip/hip_runtime.h>

// ---------------------------------------------------------------------------
// MultiheadAttention: out = (softmax((Xq Wq^T + bq)(Xb Wk^T + bk)^T / 8) (Xb Wv^T + bv)) Wo^T + bo
// B=2, S=2048, D=1024, H=16, hd=64.  All GEMMs + attention in bf16 MFMA, fp32 accum.
// ---------------------------------------------------------------------------

#define BDIM   2
#define SDIM   2048
#define DDIM   1024
#define HEADS  16
#define HD     64
#define MROWS  (BDIM * SDIM)   // 4096

typedef float  f32x4  __attribute__((ext_vector_type(4)));
typedef __bf16 bf16x8 __attribute__((ext_vector_type(8)));
typedef __bf16 bf16x4 __attribute__((ext_vector_type(4)));
typedef unsigned u32x4 __attribute__((ext_vector_type(4)));

// Q scale: 1/sqrt(hd) * log2(e)  (softmax computed in exp2 domain)
#define QSCALE 0.18033688011112042f

__device__ __forceinline__ void stage16(const void* g, void* l) {
    // global -> LDS direct copy, 16B per lane, dest = wave-uniform base + lane*16
    __builtin_amdgcn_global_load_lds((const __attribute__((address_space(1))) void*)g,
                                     (__attribute__((address_space(3))) void*)l,
                                     16, 0, 0);
}

// exact single-instruction softmax data path (round-13 win: −10.5 µs)
__device__ __forceinline__ float vexp2(float x) {
    float r;
    asm("v_exp_f32 %0, %1" : "=v"(r) : "v"(x));
    return r;
}
__device__ __forceinline__ unsigned pk2(float lo, float hi) {
    unsigned r;
    asm("v_cvt_pk_bf16_f32 %0, %1, %2" : "=v"(r) : "v"(lo), "v"(hi));
    return r;
}

// ---------------------------------------------------------------------------
// ALL fp32 -> bf16 conversions in ONE launch.
// chunks: query 524288, bank 524288, then 4 weights x 131072 (8 floats each).
// ---------------------------------------------------------------------------
__global__ __launch_bounds__(256) void cvt_all(
    const float* __restrict__ q, const float* __restrict__ bank,
    const float* __restrict__ Wq, const float* __restrict__ Wk,
    const float* __restrict__ Wv, const float* __restrict__ Wo,
    __bf16* __restrict__ xq, __bf16* __restrict__ xkv,
    __bf16* __restrict__ wq, __bf16* __restrict__ wk,
    __bf16* __restrict__ wv, __bf16* __restrict__ wo) {
    const int i = blockIdx.x * 256 + threadIdx.x;   // 0..1572863
    const float* in;
    __bf16* out;
    int off;
    if (i < 524288)       { in = q;    out = xq;  off = i; }
    else if (i < 1048576) { in = bank; out = xkv; off = i - 524288; }
    else {
        const int j = i - 1048576;
        const int sel = j >> 17;
        off = j & 131071;
        in  = (sel == 0) ? Wq : (sel == 1) ? Wk : (sel == 2) ? Wv : Wo;
        out = (sel == 0) ? wq : (sel == 1) ? wk : (sel == 2) ? wv : wo;
    }
    const float4* p = (const float4*)in;
    float4 a = p[2 * off];
    float4 c = p[2 * off + 1];
    bf16x8 o;
    o[0] = (__bf16)a.x; o[1] = (__bf16)a.y; o[2] = (__bf16)a.z; o[3] = (__bf16)a.w;
    o[4] = (__bf16)c.x; o[5] = (__bf16)c.y; o[6] = (__bf16)c.z; o[7] = (__bf16)c.w;
    *(bf16x8*)(out + 8 * off) = o;
}

// ---------------------------------------------------------------------------
// B^T GEMM (BK=32, 16 KB LDS/operand, 2-barrier loop), grid transposed
// (round-12 win: row-block fastest -> per-XCD A-panel locality).
// NEW (round 14): granule XOR-swizzle on the 64B-row LDS tiles.  Unswizzled,
// a ds_read_b128 by a 16-lane group hits bank-starts {0,16} -> 8-way conflict
// (measured 3.15M conflict-cycles/dispatch).  Swizzling the 16B granule with
// g' = q4 ^ ((row>>1)&3) spreads starts over {0,16}+{0,4,8,12} -> all 32
// banks covered exactly 2x; 2-way is free (m136).  (row>>1)&3 == (i15>>1)&3
// (higher row bits don't touch bits 1-2), so the XOR folds into constants.
// Staging per rule 21: linear LDS dest, source granule (t&3)^((t>>3)&3).
// out[r][n] = sum_k A[r][k] * W[n][k] + bias.
// MODE 0: 128x128 tile, grid (32,8,3); z selects {Q,K,V}; bf16 head-split out.
// MODE 2: 128x64 tile, grid (32,16), fp32 out.
// ---------------------------------------------------------------------------
template <int MODE>
__global__ __launch_bounds__(256) void gemm_bt(
    const __bf16* __restrict__ Aq, const __bf16* __restrict__ Akv,
    const __bf16* __restrict__ W0, const __bf16* __restrict__ W1,
    const __bf16* __restrict__ W2,
    const float* __restrict__ b0, const float* __restrict__ b1,
    const float* __restrict__ b2,
    __bf16* __restrict__ Qo, __bf16* __restrict__ Ko, __bf16* __restrict__ Vo,
    float* __restrict__ Fo) {
    constexpr int NF = (MODE == 2) ? 2 : 4;        // n-fragments per wave
    constexpr int NCOL = NF * 32;                  // block col-tile (64 or 128)
    __shared__ __align__(16) __bf16 ldsA[128 * 32];
    __shared__ __align__(16) __bf16 ldsB[(NCOL)*32];

    const int t = threadIdx.x;
    const int l = t & 63;
    const int w = t >> 6;
    const int z = (MODE == 0) ? (int)blockIdx.z : 0;

    const __bf16* A  = (MODE == 0 && z != 0) ? Akv : Aq;
    const __bf16* Wm = (z == 0) ? W0 : (z == 1 ? W1 : W2);
    const float*  bias = (z == 0) ? b0 : (z == 1 ? b1 : b2);

    const int row0 = blockIdx.x * 128;    // row-block fastest -> XCD-local A panel
    const int col0 = blockIdx.y * NCOL;

    // staging: thread t fills LDS row t>>2 (64B), granule t&3; source granule
    // XOR'd with (row>>1)&3 so the linear LDS write lands swizzled data.
    const int sg = (t & 3) ^ ((t >> 3) & 3);
    const __bf16* ga = A  + (size_t)(row0 + (t >> 2)) * DDIM + sg * 8;
    const __bf16* gb = Wm + (size_t)(col0 + (t >> 2)) * DDIM + sg * 8;
    __bf16* la = ldsA + (t & ~63) * 8;  // wave-uniform base
    __bf16* lb = ldsB + (t & ~63) * 8;

    const int wm = w >> 1, wn = w & 1;
    const int i15 = l & 15;
    const int q4 = l >> 4;
    const int gx = q4 ^ ((i15 >> 1) & 3);          // swizzled read granule

    const int aoff = (wm * 64 + i15) * 32 + gx * 8;
    const int boff = (wn * (NF * 16) + i15) * 32 + gx * 8;

    f32x4 acc[4][NF] = {};

    for (int kb = 0; kb < DDIM; kb += 32) {
        __syncthreads();
        stage16(ga + kb,             la);
        stage16(ga + kb + 64 * DDIM, la + 2048);
        stage16(gb + kb,             lb);
        if constexpr (MODE == 0)
            stage16(gb + kb + 64 * DDIM, lb + 2048);
        __syncthreads();

        bf16x8 af[4], bf[NF];
#pragma unroll
        for (int m = 0; m < 4; ++m) af[m] = *(const bf16x8*)(ldsA + aoff + m * 16 * 32);
#pragma unroll
        for (int n = 0; n < NF; ++n) bf[n] = *(const bf16x8*)(ldsB + boff + n * 16 * 32);
#pragma unroll
        for (int m = 0; m < 4; ++m)
#pragma unroll
            for (int n = 0; n < NF; ++n)
                acc[m][n] = __builtin_amdgcn_mfma_f32_16x16x32_bf16(af[m], bf[n], acc[m][n], 0, 0, 0);
    }

    // ---- epilogue: C/D layout col = lane&15, row = (lane>>4)*4 + j ----
#pragma unroll
    for (int m = 0; m < 4; ++m) {
        const int rbase = row0 + wm * 64 + m * 16 + (l >> 4) * 4;
#pragma unroll
        for (int n = 0; n < NF; ++n) {
            const int col = col0 + wn * (NF * 16) + n * 16 + (l & 15);
            const float bv = bias[col];
            if constexpr (MODE == 0) {
                const int hh = col >> 6, dd = col & 63;
#pragma unroll
                for (int j = 0; j < 4; ++j) {
                    const int r = rbase + j;
                    const int b = r >> 11, s = r & 2047;
                    const float v = acc[m][n][j] + bv;
                    if (z == 0) {
                        Qo[(((b * HEADS + hh) * SDIM + s) << 6) + dd] = (__bf16)(v * QSCALE);
                    } else if (z == 1) {
                        Ko[(((b * HEADS + hh) * SDIM + s) << 6) + dd] = (__bf16)v;
                    } else {  // V stored transposed: [B,H,hd,S]
                        Vo[(((b * HEADS + hh) * HD + dd) << 11) + s] = (__bf16)v;
                    }
                }
            } else {
#pragma unroll
                for (int j = 0; j < 4; ++j) {
                    Fo[(size_t)(rbase + j) * DDIM + col] = acc[m][n][j] + bv;
                }
            }
        }
    }
}

// ---------------------------------------------------------------------------
// Flash attention v8 (unchanged from round 13): 512 blocks x 512 threads,
// KVBLK=128, XCD head-clustering, swapped QK^T + sigma-permuted K staging,
// XOR-swizzled LDS, no-max softmax via v_exp_f32, P packed via
// v_cvt_pk_bf16_f32, row-sum on the MFMA pipe.
// ---------------------------------------------------------------------------
__global__ __launch_bounds__(512) void attn_fwd(const __bf16* __restrict__ Qb,
                                                const __bf16* __restrict__ Kb,
                                                const __bf16* __restrict__ Vtb,
                                                __bf16* __restrict__ Cb) {
    __shared__ __align__(16) __bf16 ldsK[2][2][64 * 64];
    __shared__ __align__(16) __bf16 ldsV[2][2][64 * 64];

    const int t = threadIdx.x;        // 0..511
    const int l = t & 63;
    const int w = t >> 6;             // 0..7
    const int i15 = l & 15;
    const int q4 = l >> 4;

    // --- XCD head-clustering decode (bijective on 512 blocks) ---
    const int bid  = blockIdx.x;
    const int xcd  = bid & 7;
    const int wloc = bid >> 3;               // 0..63 within XCD
    const int bh   = xcd * 4 + (wloc >> 4);  // 4 (b,h) pairs per XCD
    const int qb   = wloc & 15;              // q-block within head (consecutive)
    const int b    = bh >> 4;
    const int h    = bh & 15;
    const size_t base = (size_t)bh * SDIM * HD;
    const int q0 = qb * 128;

    // Q fragments (B-operand of swapped QK^T): col=q=i15, k-dim=d
    const __bf16* qp = Qb + base + (size_t)(q0 + w * 16 + i15) * HD + q4 * 8;
    const bf16x8 qf0 = *(const bf16x8*)(qp);
    const bf16x8 qf1 = *(const bf16x8*)(qp + 32);

    // --- staging source addresses (rule 21: linear LDS dest, permuted source)
    const int r0 = t >> 3;                    // LDS row this thread fills
    const int sl = (t & 7) ^ (r0 & 7);        // source slot = phys slot ^ row&7
    const int sig0 = ((r0 >> 5) << 5) | (((r0 >> 2) & 3) << 3)
                   | (((r0 >> 4) & 1) << 2) | (r0 & 3);      // sigma-permuted K row
    const __bf16* gk = Kb  + base + (size_t)sig0 * HD + sl * 8;
    const __bf16* gv = Vtb + base + (size_t)r0 * SDIM + sl * 8;
    const int wb = (t & ~63) * 8;             // wave-uniform LDS element base

    // --- swizzled read offsets (elements), same table for K and V reads ---
    const int xr = i15 & 7;
    int off[4][2];
#pragma unroll
    for (int n = 0; n < 4; ++n)
#pragma unroll
        for (int hh = 0; hh < 2; ++hh)
            off[n][hh] = (n * 16 + i15) * 64 + (((hh * 4 + q4) ^ xr) << 3);

    // ones fragment for the MFMA row-sum
    bf16x8 ones;
#pragma unroll
    for (int j = 0; j < 8; ++j) ones[j] = (__bf16)1.0f;

    f32x4 c[4] = {};
    f32x4 lsum = {};

    // prologue: stage round 0 (two 64-row sub-tiles of K and V) into buffer 0
    stage16(gk,           &ldsK[0][0][wb]);
    stage16(gk + 64 * HD, &ldsK[0][1][wb]);
    stage16(gv,           &ldsV[0][0][wb]);
    stage16(gv + 64,      &ldsV[0][1][wb]);

#pragma unroll 2
    for (int r = 0; r < SDIM / 128; ++r) {
        const int bb = r & 1;
        __syncthreads();   // buf[bb] staged & prev compute on buf[bb^1] done

        if (r + 1 < SDIM / 128) {
            const int s0 = (r + 1) * 128;
            stage16(gk + (size_t)s0 * HD,        &ldsK[bb ^ 1][0][wb]);
            stage16(gk + (size_t)(s0 + 64) * HD, &ldsK[bb ^ 1][1][wb]);
            stage16(gv + s0,                     &ldsV[bb ^ 1][0][wb]);
            stage16(gv + s0 + 64,                &ldsV[bb ^ 1][1][wb]);
        }

        const __bf16* lk0 = &ldsK[bb][0][0];
        const __bf16* lk1 = &ldsK[bb][1][0];
        const __bf16* lv0 = &ldsV[bb][0][0];
        const __bf16* lv1 = &ldsV[bb][1][0];

        // ---- QK^T (swapped), both halves: sA/sB hold S^T[k-block n][q] ----
        f32x4 sA[4] = {}, sB[4] = {};
        __builtin_amdgcn_s_setprio(1);
#pragma unroll
        for (int n = 0; n < 4; ++n) {
            bf16x8 k0 = *(const bf16x8*)(lk0 + off[n][0]);
            bf16x8 k1 = *(const bf16x8*)(lk0 + off[n][1]);
            sA[n] = __builtin_amdgcn_mfma_f32_16x16x32_bf16(k0, qf0, sA[n], 0, 0, 0);
            sA[n] = __builtin_amdgcn_mfma_f32_16x16x32_bf16(k1, qf1, sA[n], 0, 0, 0);
        }
#pragma unroll
        for (int n = 0; n < 4; ++n) {
            bf16x8 k0 = *(const bf16x8*)(lk1 + off[n][0]);
            bf16x8 k1 = *(const bf16x8*)(lk1 + off[n][1]);
            sB[n] = __builtin_amdgcn_mfma_f32_16x16x32_bf16(k0, qf0, sB[n], 0, 0, 0);
            sB[n] = __builtin_amdgcn_mfma_f32_16x16x32_bf16(k1, qf1, sB[n], 0, 0, 0);
        }
        __builtin_amdgcn_s_setprio(0);

        // ---- softmax numerator: v_exp_f32 per score (exact exp2), then
        //      v_cvt_pk_bf16_f32 per pair -> packed P^T fragments directly ----
#pragma unroll
        for (int n = 0; n < 4; ++n)
#pragma unroll
            for (int j = 0; j < 4; ++j) {
                sA[n][j] = vexp2(sA[n][j]);
                sB[n][j] = vexp2(sB[n][j]);
            }

        u32x4 pw0, pw1, pw2, pw3;
        pw0[0] = pk2(sA[0][0], sA[0][1]); pw0[1] = pk2(sA[0][2], sA[0][3]);
        pw0[2] = pk2(sA[1][0], sA[1][1]); pw0[3] = pk2(sA[1][2], sA[1][3]);
        pw1[0] = pk2(sA[2][0], sA[2][1]); pw1[1] = pk2(sA[2][2], sA[2][3]);
        pw1[2] = pk2(sA[3][0], sA[3][1]); pw1[3] = pk2(sA[3][2], sA[3][3]);
        pw2[0] = pk2(sB[0][0], sB[0][1]); pw2[1] = pk2(sB[0][2], sB[0][3]);
        pw2[2] = pk2(sB[1][0], sB[1][1]); pw2[3] = pk2(sB[1][2], sB[1][3]);
        pw3[0] = pk2(sB[2][0], sB[2][1]); pw3[1] = pk2(sB[2][2], sB[2][3]);
        pw3[2] = pk2(sB[3][0], sB[3][1]); pw3[3] = pk2(sB[3][2], sB[3][3]);
        const bf16x8 paA0 = __builtin_bit_cast(bf16x8, pw0);
        const bf16x8 paB0 = __builtin_bit_cast(bf16x8, pw1);
        const bf16x8 paA1 = __builtin_bit_cast(bf16x8, pw2);
        const bf16x8 paB1 = __builtin_bit_cast(bf16x8, pw3);

        // ---- PV + MFMA row-sum, both halves ----
        __builtin_amdgcn_s_setprio(1);
        lsum = __builtin_amdgcn_mfma_f32_16x16x32_bf16(ones, paA0, lsum, 0, 0, 0);
        lsum = __builtin_amdgcn_mfma_f32_16x16x32_bf16(ones, paB0, lsum, 0, 0, 0);
        lsum = __builtin_amdgcn_mfma_f32_16x16x32_bf16(ones, paA1, lsum, 0, 0, 0);
        lsum = __builtin_amdgcn_mfma_f32_16x16x32_bf16(ones, paB1, lsum, 0, 0, 0);
#pragma unroll
        for (int n2 = 0; n2 < 4; ++n2) {
            bf16x8 v0 = *(const bf16x8*)(lv0 + off[n2][0]);
            bf16x8 v1 = *(const bf16x8*)(lv0 + off[n2][1]);
            c[n2] = __builtin_amdgcn_mfma_f32_16x16x32_bf16(v0, paA0, c[n2], 0, 0, 0);
            c[n2] = __builtin_amdgcn_mfma_f32_16x16x32_bf16(v1, paB0, c[n2], 0, 0, 0);
            bf16x8 u0 = *(const bf16x8*)(lv1 + off[n2][0]);
            bf16x8 u1 = *(const bf16x8*)(lv1 + off[n2][1]);
            c[n2] = __builtin_amdgcn_mfma_f32_16x16x32_bf16(u0, paA1, c[n2], 0, 0, 0);
            c[n2] = __builtin_amdgcn_mfma_f32_16x16x32_bf16(u1, paB1, c[n2], 0, 0, 0);
        }
        __builtin_amdgcn_s_setprio(0);
    }

    // ---- write ctx (merged heads, bf16): [B, S, D], 8B vector stores ----
    const float inv = 1.0f / lsum[0];
    const int q = q0 + w * 16 + i15;
#pragma unroll
    for (int n2 = 0; n2 < 4; ++n2) {
        bf16x4 o;
#pragma unroll
        for (int j = 0; j < 4; ++j) o[j] = (__bf16)(c[n2][j] * inv);
        *(bf16x4*)(Cb + (size_t)(b * SDIM + q) * DDIM + h * HD + n2 * 16 + q4 * 4) = o;
    }
}

// ---------------------------------------------------------------------------
extern "C" void kernel_launch(void* const* d_in, const int* in_sizes, int n_in,
                              void* d_out, int out_size, void* d_ws, size_t ws_size,
                              hipStream_t stream) {
    const float* query = (const float*)d_in[0];
    const float* bank  = (const float*)d_in[1];
    const float* Wq = (const float*)d_in[2];
    const float* bq = (const float*)d_in[3];
    const float* Wk = (const float*)d_in[4];
    const float* bk = (const float*)d_in[5];
    const float* Wv = (const float*)d_in[6];
    const float* bv = (const float*)d_in[7];
    const float* Wo = (const float*)d_in[8];
    const float* bo = (const float*)d_in[9];
    float* out = (float*)d_out;

    char* ws = (char*)d_ws;
    __bf16* xq  = (__bf16*)(ws);                    // 8 MB  [4096,1024] (reused as ctx)
    __bf16* xkv = (__bf16*)(ws + (8u  << 20));      // 8 MB
    __bf16* wq  = (__bf16*)(ws + (16u << 20));      // 2 MB
    __bf16* wk  = (__bf16*)(ws + (18u << 20));      // 2 MB
    __bf16* wv  = (__bf16*)(ws + (20u << 20));      // 2 MB
    __bf16* wo  = (__bf16*)(ws + (22u << 20));      // 2 MB
    __bf16* qbuf = (__bf16*)(ws + (24u << 20));     // 8 MB [B,H,S,hd] (scaled)
    __bf16* kbuf = (__bf16*)(ws + (32u << 20));     // 8 MB [B,H,S,hd]
    __bf16* vtbuf = (__bf16*)(ws + (40u << 20));    // 8 MB [B,H,hd,S]
    __bf16* ctx = xq;                               // alias: xq dead after QKV gemm

    // fp32 -> bf16 (single launch for all 6 tensors)
    cvt_all<<<6144, 256, 0, stream>>>(query, bank, Wq, Wk, Wv, Wo,
                                      xq, xkv, wq, wk, wv, wo);

    // fused QKV projections — row-block-fastest grid (A-panel XCD locality)
    gemm_bt<0><<<dim3(32, 8, 3), 256, 0, stream>>>(
        xq, xkv, wq, wk, wv, bq, bk, bv, qbuf, kbuf, vtbuf, nullptr);

    // flash attention (1D grid, XCD head-clustering decode inside)
    attn_fwd<<<512, 512, 0, stream>>>(qbuf, kbuf, vtbuf, ctx);

    // output projection (fp32 out) — row-block-fastest grid
    gemm_bt<2><<<dim3(32, 16, 1), 256, 0, stream>>>(
        ctx, nullptr, wo, nullptr, nullptr, bo, nullptr, nullptr,
        nullptr, nullptr, nullptr, out);
}

// Round 15
// 112.216 us; speedup vs baseline: 1.2182x; 1.0013x over previous
//
#include <hip/hip_runtime.h>

// ---------------------------------------------------------------------------
// MultiheadAttention: out = (softmax((Xq Wq^T + bq)(Xb Wk^T + bk)^T / 8) (Xb Wv^T + bv)) Wo^T + bo
// B=2, S=2048, D=1024, H=16, hd=64.  All GEMMs + attention in bf16 MFMA, fp32 accum.
// ---------------------------------------------------------------------------

#define BDIM   2
#define SDIM   2048
#define DDIM   1024
#define HEADS  16
#define HD     64
#define MROWS  (BDIM * SDIM)   // 4096

typedef float  f32x4  __attribute__((ext_vector_type(4)));
typedef __bf16 bf16x8 __attribute__((ext_vector_type(8)));
typedef __bf16 bf16x4 __attribute__((ext_vector_type(4)));
typedef unsigned u32x4 __attribute__((ext_vector_type(4)));

// Q scale: 1/sqrt(hd) * log2(e)  (softmax computed in exp2 domain)
#define QSCALE 0.18033688011112042f

__device__ __forceinline__ void stage16(const void* g, void* l) {
    // global -> LDS direct copy, 16B per lane, dest = wave-uniform base + lane*16
    __builtin_amdgcn_global_load_lds((const __attribute__((address_space(1))) void*)g,
                                     (__attribute__((address_space(3))) void*)l,
                                     16, 0, 0);
}

// exact single-instruction softmax data path (round-13 win: −10.5 µs)
__device__ __forceinline__ float vexp2(float x) {
    float r;
    asm("v_exp_f32 %0, %1" : "=v"(r) : "v"(x));
    return r;
}
__device__ __forceinline__ unsigned pk2(float lo, float hi) {
    unsigned r;
    asm("v_cvt_pk_bf16_f32 %0, %1, %2" : "=v"(r) : "v"(lo), "v"(hi));
    return r;
}

// ---------------------------------------------------------------------------
// ALL fp32 -> bf16 conversions in ONE launch.
// chunks: query 524288, bank 524288, then 4 weights x 131072 (8 floats each).
// ---------------------------------------------------------------------------
__global__ __launch_bounds__(256) void cvt_all(
    const float* __restrict__ q, const float* __restrict__ bank,
    const float* __restrict__ Wq, const float* __restrict__ Wk,
    const float* __restrict__ Wv, const float* __restrict__ Wo,
    __bf16* __restrict__ xq, __bf16* __restrict__ xkv,
    __bf16* __restrict__ wq, __bf16* __restrict__ wk,
    __bf16* __restrict__ wv, __bf16* __restrict__ wo) {
    const int i = blockIdx.x * 256 + threadIdx.x;   // 0..1572863
    const float* in;
    __bf16* out;
    int off;
    if (i < 524288)       { in = q;    out = xq;  off = i; }
    else if (i < 1048576) { in = bank; out = xkv; off = i - 524288; }
    else {
        const int j = i - 1048576;
        const int sel = j >> 17;
        off = j & 131071;
        in  = (sel == 0) ? Wq : (sel == 1) ? Wk : (sel == 2) ? Wv : Wo;
        out = (sel == 0) ? wq : (sel == 1) ? wk : (sel == 2) ? wv : wo;
    }
    const float4* p = (const float4*)in;
    float4 a = p[2 * off];
    float4 c = p[2 * off + 1];
    bf16x8 o;
    o[0] = (__bf16)a.x; o[1] = (__bf16)a.y; o[2] = (__bf16)a.z; o[3] = (__bf16)a.w;
    o[4] = (__bf16)c.x; o[5] = (__bf16)c.y; o[6] = (__bf16)c.z; o[7] = (__bf16)c.w;
    *(bf16x8*)(out + 8 * off) = o;
}

// ---------------------------------------------------------------------------
// B^T GEMM (BK=32, 16 KB LDS/operand, 2-barrier loop), grid transposed
// (round-12: row-block fastest -> per-XCD A-panel locality), granule
// XOR-swizzle (round-14: conflicts 3.15M -> 0).
// out[r][n] = sum_k A[r][k] * W[n][k] + bias.
// MODE 0: 128x128 tile, grid (32,8,3); z selects {Q,K,V}; bf16 head-split out.
// MODE 2: 128x64 tile, grid (32,16), fp32 out.
// ---------------------------------------------------------------------------
template <int MODE>
__global__ __launch_bounds__(256) void gemm_bt(
    const __bf16* __restrict__ Aq, const __bf16* __restrict__ Akv,
    const __bf16* __restrict__ W0, const __bf16* __restrict__ W1,
    const __bf16* __restrict__ W2,
    const float* __restrict__ b0, const float* __restrict__ b1,
    const float* __restrict__ b2,
    __bf16* __restrict__ Qo, __bf16* __restrict__ Ko, __bf16* __restrict__ Vo,
    float* __restrict__ Fo) {
    constexpr int NF = (MODE == 2) ? 2 : 4;        // n-fragments per wave
    constexpr int NCOL = NF * 32;                  // block col-tile (64 or 128)
    __shared__ __align__(16) __bf16 ldsA[128 * 32];
    __shared__ __align__(16) __bf16 ldsB[(NCOL)*32];

    const int t = threadIdx.x;
    const int l = t & 63;
    const int w = t >> 6;
    const int z = (MODE == 0) ? (int)blockIdx.z : 0;

    const __bf16* A  = (MODE == 0 && z != 0) ? Akv : Aq;
    const __bf16* Wm = (z == 0) ? W0 : (z == 1 ? W1 : W2);
    const float*  bias = (z == 0) ? b0 : (z == 1 ? b1 : b2);

    const int row0 = blockIdx.x * 128;    // row-block fastest -> XCD-local A panel
    const int col0 = blockIdx.y * NCOL;

    // staging: linear LDS dest; source granule XOR'd with (row>>1)&3 (rule 21)
    const int sg = (t & 3) ^ ((t >> 3) & 3);
    const __bf16* ga = A  + (size_t)(row0 + (t >> 2)) * DDIM + sg * 8;
    const __bf16* gb = Wm + (size_t)(col0 + (t >> 2)) * DDIM + sg * 8;
    __bf16* la = ldsA + (t & ~63) * 8;  // wave-uniform base
    __bf16* lb = ldsB + (t & ~63) * 8;

    const int wm = w >> 1, wn = w & 1;
    const int i15 = l & 15;
    const int q4 = l >> 4;
    const int gx = q4 ^ ((i15 >> 1) & 3);          // swizzled read granule

    const int aoff = (wm * 64 + i15) * 32 + gx * 8;
    const int boff = (wn * (NF * 16) + i15) * 32 + gx * 8;

    f32x4 acc[4][NF] = {};

    for (int kb = 0; kb < DDIM; kb += 32) {
        __syncthreads();
        stage16(ga + kb,             la);
        stage16(ga + kb + 64 * DDIM, la + 2048);
        stage16(gb + kb,             lb);
        if constexpr (MODE == 0)
            stage16(gb + kb + 64 * DDIM, lb + 2048);
        __syncthreads();

        bf16x8 af[4], bf[NF];
#pragma unroll
        for (int m = 0; m < 4; ++m) af[m] = *(const bf16x8*)(ldsA + aoff + m * 16 * 32);
#pragma unroll
        for (int n = 0; n < NF; ++n) bf[n] = *(const bf16x8*)(ldsB + boff + n * 16 * 32);
#pragma unroll
        for (int m = 0; m < 4; ++m)
#pragma unroll
            for (int n = 0; n < NF; ++n)
                acc[m][n] = __builtin_amdgcn_mfma_f32_16x16x32_bf16(af[m], bf[n], acc[m][n], 0, 0, 0);
    }

    // ---- epilogue: C/D layout col = lane&15, row = (lane>>4)*4 + j ----
#pragma unroll
    for (int m = 0; m < 4; ++m) {
        const int rbase = row0 + wm * 64 + m * 16 + (l >> 4) * 4;
#pragma unroll
        for (int n = 0; n < NF; ++n) {
            const int col = col0 + wn * (NF * 16) + n * 16 + (l & 15);
            const float bv = bias[col];
            if constexpr (MODE == 0) {
                const int hh = col >> 6, dd = col & 63;
#pragma unroll
                for (int j = 0; j < 4; ++j) {
                    const int r = rbase + j;
                    const int b = r >> 11, s = r & 2047;
                    const float v = acc[m][n][j] + bv;
                    if (z == 0) {
                        Qo[(((b * HEADS + hh) * SDIM + s) << 6) + dd] = (__bf16)(v * QSCALE);
                    } else if (z == 1) {
                        Ko[(((b * HEADS + hh) * SDIM + s) << 6) + dd] = (__bf16)v;
                    } else {  // V stored transposed: [B,H,hd,S]
                        Vo[(((b * HEADS + hh) * HD + dd) << 11) + s] = (__bf16)v;
                    }
                }
            } else {
#pragma unroll
                for (int j = 0; j < 4; ++j) {
                    Fo[(size_t)(rbase + j) * DDIM + col] = acc[m][n][j] + bv;
                }
            }
        }
    }
}

// ---------------------------------------------------------------------------
// Flash attention v9: DUAL-Q waves — 512 blocks x 256 threads = 4 waves x
// 32 q-rows (fragments u=0 at w*16, u=1 at +64; Q-tile 128).  Each K/V
// ds_read_b128 now feeds TWO MFMAs -> LDS read traffic per CU HALVES
// (512 -> 256 KB/round; v8 was LDS-BW-bound at ~27 µs floor).  2 blocks/CU
// preserved (64 KB LDS) so cross-block barrier overlap survives.  v4's
// dual-q failed with the fat serial softmax; v9's softmax is branch-free
// v_exp_f32 + v_cvt_pk_bf16_f32 (round-13), MFMA row-sum, no cross-lane.
// KVBLK=128, XCD head-clustering, swapped QK^T + sigma-permuted K staging,
// XOR-swizzled LDS via pre-swizzled global source.
// ---------------------------------------------------------------------------
__global__ __launch_bounds__(256) void attn_fwd(const __bf16* __restrict__ Qb,
                                                const __bf16* __restrict__ Kb,
                                                const __bf16* __restrict__ Vtb,
                                                __bf16* __restrict__ Cb) {
    __shared__ __align__(16) __bf16 ldsK[2][2][64 * 64];
    __shared__ __align__(16) __bf16 ldsV[2][2][64 * 64];

    const int t = threadIdx.x;        // 0..255
    const int l = t & 63;
    const int w = t >> 6;             // 0..3
    const int i15 = l & 15;
    const int q4 = l >> 4;

    // --- XCD head-clustering decode (bijective on 512 blocks) ---
    const int bid  = blockIdx.x;
    const int xcd  = bid & 7;
    const int wloc = bid >> 3;               // 0..63 within XCD
    const int bh   = xcd * 4 + (wloc >> 4);  // 4 (b,h) pairs per XCD
    const int qb   = wloc & 15;              // q-block within head (consecutive)
    const int b    = bh >> 4;
    const int h    = bh & 15;
    const size_t base = (size_t)bh * SDIM * HD;
    const int q0 = qb * 128;

    // Q fragments (B-operand of swapped QK^T): u=0 rows q0+w*16.., u=1 at +64
    const __bf16* qp = Qb + base + (size_t)(q0 + w * 16 + i15) * HD + q4 * 8;
    const bf16x8 qf00 = *(const bf16x8*)(qp);
    const bf16x8 qf01 = *(const bf16x8*)(qp + 32);
    const bf16x8 qf10 = *(const bf16x8*)(qp + 64 * HD);
    const bf16x8 qf11 = *(const bf16x8*)(qp + 64 * HD + 32);

    // --- staging source addresses (rule 21: linear LDS dest, permuted source)
    // 256 threads cover half an 8 KB sub-tile per stage16 call (2 calls/sub-tile).
    const int r0 = t >> 3;                    // LDS row this thread fills (0..31)
    const int sl = (t & 7) ^ (r0 & 7);        // source slot = phys slot ^ row&7
    const int sig0 = (((r0 >> 2) & 3) << 3) | (((r0 >> 4) & 1) << 2) | (r0 & 3);
    const __bf16* gk = Kb  + base + (size_t)sig0 * HD + sl * 8;  // sigma K rows
    const __bf16* gv = Vtb + base + (size_t)r0 * SDIM + sl * 8;  // identity V rows
    const int wb = (t & ~63) * 8;             // wave-uniform LDS element base

    // --- swizzled read offsets (elements), same table for K and V reads ---
    const int xr = i15 & 7;
    int off[4][2];
#pragma unroll
    for (int n = 0; n < 4; ++n)
#pragma unroll
        for (int hh = 0; hh < 2; ++hh)
            off[n][hh] = (n * 16 + i15) * 64 + (((hh * 4 + q4) ^ xr) << 3);

    // ones fragment for the MFMA row-sum
    bf16x8 ones;
#pragma unroll
    for (int j = 0; j < 8; ++j) ones[j] = (__bf16)1.0f;

    f32x4 c0[4] = {}, c1[4] = {};
    f32x4 ls0 = {}, ls1 = {};

    // prologue: stage round 0 (K and V, two 64x64 sub-tiles each) into buf 0
    stage16(gk,                       &ldsK[0][0][wb]);
    stage16(gk + 32 * HD,             &ldsK[0][0][wb + 2048]);
    stage16(gk + 64 * HD,             &ldsK[0][1][wb]);
    stage16(gk + 96 * HD,             &ldsK[0][1][wb + 2048]);
    stage16(gv,                       &ldsV[0][0][wb]);
    stage16(gv + (size_t)32 * SDIM,   &ldsV[0][0][wb + 2048]);
    stage16(gv + 64,                  &ldsV[0][1][wb]);
    stage16(gv + 64 + (size_t)32 * SDIM, &ldsV[0][1][wb + 2048]);

#pragma unroll 2
    for (int r = 0; r < SDIM / 128; ++r) {
        const int bb = r & 1;
        __syncthreads();   // buf[bb] staged & prev compute on buf[bb^1] done

        if (r + 1 < SDIM / 128) {
            const int s0 = (r + 1) * 128;
            stage16(gk + (size_t)(s0)*HD,          &ldsK[bb ^ 1][0][wb]);
            stage16(gk + (size_t)(s0 + 32) * HD,   &ldsK[bb ^ 1][0][wb + 2048]);
            stage16(gk + (size_t)(s0 + 64) * HD,   &ldsK[bb ^ 1][1][wb]);
            stage16(gk + (size_t)(s0 + 96) * HD,   &ldsK[bb ^ 1][1][wb + 2048]);
            stage16(gv + s0,                       &ldsV[bb ^ 1][0][wb]);
            stage16(gv + s0 + (size_t)32 * SDIM,   &ldsV[bb ^ 1][0][wb + 2048]);
            stage16(gv + s0 + 64,                  &ldsV[bb ^ 1][1][wb]);
            stage16(gv + s0 + 64 + (size_t)32 * SDIM, &ldsV[bb ^ 1][1][wb + 2048]);
        }

        const __bf16* lk0 = &ldsK[bb][0][0];
        const __bf16* lk1 = &ldsK[bb][1][0];
        const __bf16* lv0 = &ldsV[bb][0][0];
        const __bf16* lv1 = &ldsV[bb][1][0];

        // ---- QK^T (swapped): each K read feeds BOTH q-fragments ----
        f32x4 sA[4] = {}, sB[4] = {}, sC[4] = {}, sD[4] = {};
        __builtin_amdgcn_s_setprio(1);
#pragma unroll
        for (int n = 0; n < 4; ++n) {
            bf16x8 k0 = *(const bf16x8*)(lk0 + off[n][0]);
            bf16x8 k1 = *(const bf16x8*)(lk0 + off[n][1]);
            sA[n] = __builtin_amdgcn_mfma_f32_16x16x32_bf16(k0, qf00, sA[n], 0, 0, 0);
            sC[n] = __builtin_amdgcn_mfma_f32_16x16x32_bf16(k0, qf10, sC[n], 0, 0, 0);
            sA[n] = __builtin_amdgcn_mfma_f32_16x16x32_bf16(k1, qf01, sA[n], 0, 0, 0);
            sC[n] = __builtin_amdgcn_mfma_f32_16x16x32_bf16(k1, qf11, sC[n], 0, 0, 0);
        }
#pragma unroll
        for (int n = 0; n < 4; ++n) {
            bf16x8 k0 = *(const bf16x8*)(lk1 + off[n][0]);
            bf16x8 k1 = *(const bf16x8*)(lk1 + off[n][1]);
            sB[n] = __builtin_amdgcn_mfma_f32_16x16x32_bf16(k0, qf00, sB[n], 0, 0, 0);
            sD[n] = __builtin_amdgcn_mfma_f32_16x16x32_bf16(k0, qf10, sD[n], 0, 0, 0);
            sB[n] = __builtin_amdgcn_mfma_f32_16x16x32_bf16(k1, qf01, sB[n], 0, 0, 0);
            sD[n] = __builtin_amdgcn_mfma_f32_16x16x32_bf16(k1, qf11, sD[n], 0, 0, 0);
        }
        __builtin_amdgcn_s_setprio(0);

        // ---- softmax numerator: v_exp_f32 per score, both fragments ----
#pragma unroll
        for (int n = 0; n < 4; ++n)
#pragma unroll
            for (int j = 0; j < 4; ++j) {
                sA[n][j] = vexp2(sA[n][j]);
                sB[n][j] = vexp2(sB[n][j]);
                sC[n][j] = vexp2(sC[n][j]);
                sD[n][j] = vexp2(sD[n][j]);
            }

        // ---- pack P^T fragments via v_cvt_pk_bf16_f32 ----
        u32x4 w0, w1, w2, w3, w4, w5, w6, w7;
        w0[0] = pk2(sA[0][0], sA[0][1]); w0[1] = pk2(sA[0][2], sA[0][3]);
        w0[2] = pk2(sA[1][0], sA[1][1]); w0[3] = pk2(sA[1][2], sA[1][3]);
        w1[0] = pk2(sA[2][0], sA[2][1]); w1[1] = pk2(sA[2][2], sA[2][3]);
        w1[2] = pk2(sA[3][0], sA[3][1]); w1[3] = pk2(sA[3][2], sA[3][3]);
        w2[0] = pk2(sB[0][0], sB[0][1]); w2[1] = pk2(sB[0][2], sB[0][3]);
        w2[2] = pk2(sB[1][0], sB[1][1]); w2[3] = pk2(sB[1][2], sB[1][3]);
        w3[0] = pk2(sB[2][0], sB[2][1]); w3[1] = pk2(sB[2][2], sB[2][3]);
        w3[2] = pk2(sB[3][0], sB[3][1]); w3[3] = pk2(sB[3][2], sB[3][3]);
        w4[0] = pk2(sC[0][0], sC[0][1]); w4[1] = pk2(sC[0][2], sC[0][3]);
        w4[2] = pk2(sC[1][0], sC[1][1]); w4[3] = pk2(sC[1][2], sC[1][3]);
        w5[0] = pk2(sC[2][0], sC[2][1]); w5[1] = pk2(sC[2][2], sC[2][3]);
        w5[2] = pk2(sC[3][0], sC[3][1]); w5[3] = pk2(sC[3][2], sC[3][3]);
        w6[0] = pk2(sD[0][0], sD[0][1]); w6[1] = pk2(sD[0][2], sD[0][3]);
        w6[2] = pk2(sD[1][0], sD[1][1]); w6[3] = pk2(sD[1][2], sD[1][3]);
        w7[0] = pk2(sD[2][0], sD[2][1]); w7[1] = pk2(sD[2][2], sD[2][3]);
        w7[2] = pk2(sD[3][0], sD[3][1]); w7[3] = pk2(sD[3][2], sD[3][3]);
        const bf16x8 pA = __builtin_bit_cast(bf16x8, w0);  // f0, Ksub0 k0-31
        const bf16x8 pB = __builtin_bit_cast(bf16x8, w1);  // f0, Ksub0 k32-63
        const bf16x8 pC = __builtin_bit_cast(bf16x8, w2);  // f0, Ksub1 k0-31
        const bf16x8 pD = __builtin_bit_cast(bf16x8, w3);  // f0, Ksub1 k32-63
        const bf16x8 rA = __builtin_bit_cast(bf16x8, w4);  // f1 ...
        const bf16x8 rB = __builtin_bit_cast(bf16x8, w5);
        const bf16x8 rC = __builtin_bit_cast(bf16x8, w6);
        const bf16x8 rD = __builtin_bit_cast(bf16x8, w7);

        // ---- PV + MFMA row-sum: each V read feeds BOTH q-fragments ----
        __builtin_amdgcn_s_setprio(1);
        ls0 = __builtin_amdgcn_mfma_f32_16x16x32_bf16(ones, pA, ls0, 0, 0, 0);
        ls0 = __builtin_amdgcn_mfma_f32_16x16x32_bf16(ones, pB, ls0, 0, 0, 0);
        ls0 = __builtin_amdgcn_mfma_f32_16x16x32_bf16(ones, pC, ls0, 0, 0, 0);
        ls0 = __builtin_amdgcn_mfma_f32_16x16x32_bf16(ones, pD, ls0, 0, 0, 0);
        ls1 = __builtin_amdgcn_mfma_f32_16x16x32_bf16(ones, rA, ls1, 0, 0, 0);
        ls1 = __builtin_amdgcn_mfma_f32_16x16x32_bf16(ones, rB, ls1, 0, 0, 0);
        ls1 = __builtin_amdgcn_mfma_f32_16x16x32_bf16(ones, rC, ls1, 0, 0, 0);
        ls1 = __builtin_amdgcn_mfma_f32_16x16x32_bf16(ones, rD, ls1, 0, 0, 0);
#pragma unroll
        for (int n2 = 0; n2 < 4; ++n2) {
            bf16x8 v0 = *(const bf16x8*)(lv0 + off[n2][0]);
            bf16x8 v1 = *(const bf16x8*)(lv0 + off[n2][1]);
            c0[n2] = __builtin_amdgcn_mfma_f32_16x16x32_bf16(v0, pA, c0[n2], 0, 0, 0);
            c1[n2] = __builtin_amdgcn_mfma_f32_16x16x32_bf16(v0, rA, c1[n2], 0, 0, 0);
            c0[n2] = __builtin_amdgcn_mfma_f32_16x16x32_bf16(v1, pB, c0[n2], 0, 0, 0);
            c1[n2] = __builtin_amdgcn_mfma_f32_16x16x32_bf16(v1, rB, c1[n2], 0, 0, 0);
            bf16x8 u0 = *(const bf16x8*)(lv1 + off[n2][0]);
            bf16x8 u1 = *(const bf16x8*)(lv1 + off[n2][1]);
            c0[n2] = __builtin_amdgcn_mfma_f32_16x16x32_bf16(u0, pC, c0[n2], 0, 0, 0);
            c1[n2] = __builtin_amdgcn_mfma_f32_16x16x32_bf16(u0, rC, c1[n2], 0, 0, 0);
            c0[n2] = __builtin_amdgcn_mfma_f32_16x16x32_bf16(u1, pD, c0[n2], 0, 0, 0);
            c1[n2] = __builtin_amdgcn_mfma_f32_16x16x32_bf16(u1, rD, c1[n2], 0, 0, 0);
        }
        __builtin_amdgcn_s_setprio(0);
    }

    // ---- write ctx (merged heads, bf16): [B, S, D], 8B vector stores ----
    const float inv0 = 1.0f / ls0[0];
    const float inv1 = 1.0f / ls1[0];
    const int q = q0 + w * 16 + i15;
#pragma unroll
    for (int n2 = 0; n2 < 4; ++n2) {
        bf16x4 oA, oB;
#pragma unroll
        for (int j = 0; j < 4; ++j) {
            oA[j] = (__bf16)(c0[n2][j] * inv0);
            oB[j] = (__bf16)(c1[n2][j] * inv1);
        }
        *(bf16x4*)(Cb + (size_t)(b * SDIM + q) * DDIM + h * HD + n2 * 16 + q4 * 4) = oA;
        *(bf16x4*)(Cb + (size_t)(b * SDIM + q + 64) * DDIM + h * HD + n2 * 16 + q4 * 4) = oB;
    }
}

// ---------------------------------------------------------------------------
extern "C" void kernel_launch(void* const* d_in, const int* in_sizes, int n_in,
                              void* d_out, int out_size, void* d_ws, size_t ws_size,
                              hipStream_t stream) {
    const float* query = (const float*)d_in[0];
    const float* bank  = (const float*)d_in[1];
    const float* Wq = (const float*)d_in[2];
    const float* bq = (const float*)d_in[3];
    const float* Wk = (const float*)d_in[4];
    const float* bk = (const float*)d_in[5];
    const float* Wv = (const float*)d_in[6];
    const float* bv = (const float*)d_in[7];
    const float* Wo = (const float*)d_in[8];
    const float* bo = (const float*)d_in[9];
    float* out = (float*)d_out;

    char* ws = (char*)d_ws;
    __bf16* xq  = (__bf16*)(ws);                    // 8 MB  [4096,1024] (reused as ctx)
    __bf16* xkv = (__bf16*)(ws + (8u  << 20));      // 8 MB
    __bf16* wq  = (__bf16*)(ws + (16u << 20));      // 2 MB
    __bf16* wk  = (__bf16*)(ws + (18u << 20));      // 2 MB
    __bf16* wv  = (__bf16*)(ws + (20u << 20));      // 2 MB
    __bf16* wo  = (__bf16*)(ws + (22u << 20));      // 2 MB
    __bf16* qbuf = (__bf16*)(ws + (24u << 20));     // 8 MB [B,H,S,hd] (scaled)
    __bf16* kbuf = (__bf16*)(ws + (32u << 20));     // 8 MB [B,H,S,hd]
    __bf16* vtbuf = (__bf16*)(ws + (40u << 20));    // 8 MB [B,H,hd,S]
    __bf16* ctx = xq;                               // alias: xq dead after QKV gemm

    // fp32 -> bf16 (single launch for all 6 tensors)
    cvt_all<<<6144, 256, 0, stream>>>(query, bank, Wq, Wk, Wv, Wo,
                                      xq, xkv, wq, wk, wv, wo);

    // fused QKV projections — row-block-fastest grid (A-panel XCD locality)
    gemm_bt<0><<<dim3(32, 8, 3), 256, 0, stream>>>(
        xq, xkv, wq, wk, wv, bq, bk, bv, qbuf, kbuf, vtbuf, nullptr);

    // flash attention v9 (dual-q waves, 256 threads)
    attn_fwd<<<512, 256, 0, stream>>>(qbuf, kbuf, vtbuf, ctx);

    // output projection (fp32 out) — row-block-fastest grid
    gemm_bt<2><<<dim3(32, 16, 1), 256, 0, stream>>>(
        ctx, nullptr, wo, nullptr, nullptr, bo, nullptr, nullptr,
        nullptr, nullptr, nullptr, out);
}